// Round 7
// baseline (243.981 us; speedup 1.0000x reference)
//
#include <hip/hip_runtime.h>

#define B_ 2
#define S_ 2048
#define E_ 1024
#define H_ 16
#define D_ 64
#define M_ (B_*S_)
#define K_ E_

typedef __attribute__((ext_vector_type(8))) short  short8;
typedef __attribute__((ext_vector_type(4))) float  f32x4;
typedef __attribute__((ext_vector_type(8))) unsigned short u16x8;
typedef __attribute__((ext_vector_type(4))) unsigned short u16x4;
typedef __attribute__((ext_vector_type(4))) unsigned int   u32x4;

// 0.125 * log2(e): folded into Q so scores arrive in exp2 domain
#define QSCALE 0.18033688011112042f

#if __has_builtin(__builtin_amdgcn_exp2f)
#define EXP2F(x) __builtin_amdgcn_exp2f(x)   // raw v_exp_f32
#else
#define EXP2F(x) exp2f(x)
#endif

__device__ __forceinline__ unsigned short f2bf(float f) {   // RNE
    unsigned u = __float_as_uint(f);
    u += 0x7fffu + ((u >> 16) & 1u);
    return (unsigned short)(u >> 16);
}

// 2x f32 -> packed bf16 in one instruction (lo=a, hi=b), RNE.
__device__ __forceinline__ unsigned cvtpk(float a, float b) {
    unsigned r;
    asm("v_cvt_pk_bf16_f32 %0, %1, %2" : "=v"(r) : "v"(a), "v"(b));
    return r;
}

__device__ __forceinline__ void gl_lds16(const ushort* g, ushort* l) {
    __builtin_amdgcn_global_load_lds((const __attribute__((address_space(1))) void*)g,
                                     (__attribute__((address_space(3))) void*)l,
                                     16, 0, 0);
}

// counted-vmcnt barrier: wait for all but the newest N vmem ops, then raw
// s_barrier (no compiler vmcnt(0) drain -- the whole point).
#define FL_SYNC(N) do {                                                   \
    asm volatile("s_waitcnt vmcnt(" #N ")" ::: "memory");                 \
    __builtin_amdgcn_s_barrier();                                         \
    asm volatile("" ::: "memory");                                        \
} while (0)

#define WAITL0_BAR() do {                                                 \
    asm volatile("s_waitcnt lgkmcnt(0)" ::: "memory");                    \
    __builtin_amdgcn_s_barrier();                                         \
    asm volatile("" ::: "memory");                                        \
} while (0)

// ---------------------------------------------------------------------------
// fp32 -> bf16 conversion (all inputs).
// ---------------------------------------------------------------------------
__global__ __launch_bounds__(256)
void cvt_all(const float* __restrict__ q, const float* __restrict__ k,
             const float* __restrict__ v, const float* __restrict__ wq,
             const float* __restrict__ wk, const float* __restrict__ wv,
             const float* __restrict__ wo, ushort* __restrict__ dst)
{
    const int bid = blockIdx.x;
    const float* src;
    size_t dof;
    int local;
    if (bid < 6144) {
        const int t = bid >> 11;
        src = (t == 0) ? q : (t == 1) ? k : v;
        dof = (size_t)t * 4194304u;
        local = bid & 2047;
    } else {
        const int r = bid - 6144;
        const int t = r >> 9;
        src = (t == 0) ? wq : (t == 1) ? wk : (t == 2) ? wv : wo;
        dof = 12582912u + (size_t)t * 1048576u;
        local = r & 511;
    }
    const size_t idx = (size_t)local * 2048 + threadIdx.x * 8;
    const float4 a = *(const float4*)(src + idx);
    const float4 b = *(const float4*)(src + idx + 4);
    u16x8 o;
    o[0] = f2bf(a.x); o[1] = f2bf(a.y); o[2] = f2bf(a.z); o[3] = f2bf(a.w);
    o[4] = f2bf(b.x); o[5] = f2bf(b.y); o[6] = f2bf(b.z); o[7] = f2bf(b.w);
    *(u16x8*)(dst + dof + idx) = o;
}

// ---------------------------------------------------------------------------
// 256x256xBK64 pipelined GEMM core for the QKV projections (R3, kept).
// ---------------------------------------------------------------------------
template<int SWAP>
__device__ __forceinline__ void qkv_core(const ushort* __restrict__ X,
                                         const ushort* __restrict__ W,
                                         int m0, int n0,
                                         f32x4 acc[8][4], ushort* sh)
{
    const int tid  = threadIdx.x;
    const int lane = tid & 63;
    const int w    = tid >> 6;          // 0..7
    const int wm   = w & 1;             // 2 M-waves
    const int wn   = w >> 1;            // 4 N-waves
    const int l15  = lane & 15, quad = lane >> 4;

    const int srow = lane >> 3, schunk = lane & 7;
    const int scol = (schunk ^ srow) * 8;          // row&7 == srow
    const ushort* pa[4]; const ushort* pb[4]; int loff[4];
    #pragma unroll
    for (int i = 0; i < 4; ++i) {
        const int row = (w * 4 + i) * 8 + srow;
        pa[i] = X + (size_t)(m0 + row) * K_ + scol;
        pb[i] = W + (size_t)(n0 + row) * K_ + scol;
        loff[i] = (w * 4 + i) * 512 + lane * 8;
    }

    const f32x4 zero = {0.f, 0.f, 0.f, 0.f};
    #pragma unroll
    for (int mt = 0; mt < 8; ++mt)
        #pragma unroll
        for (int nt = 0; nt < 4; ++nt) acc[mt][nt] = zero;

    #pragma unroll
    for (int i = 0; i < 4; ++i) {
        gl_lds16(pa[i],      sh + loff[i]);
        gl_lds16(pb[i],      sh + 16384 + loff[i]);
    }
    #pragma unroll
    for (int i = 0; i < 4; ++i) {
        gl_lds16(pa[i] + 64, sh + 32768 + loff[i]);
        gl_lds16(pb[i] + 64, sh + 32768 + 16384 + loff[i]);
    }

    const int arow = wm * 128 + l15;               // + mt*16
    const int brow = wn * 64 + l15;                // + nt*16

    for (int t = 0; t < 16; ++t) {
        ushort* curA = sh + (t & 1) * 32768;
        ushort* curB = curA + 16384;

        if (t < 15) { FL_SYNC(8); } else { FL_SYNC(0); }

        __builtin_amdgcn_s_setprio(1);
        #pragma unroll
        for (int kc = 0; kc < 2; ++kc) {
            short8 bf[4];
            #pragma unroll
            for (int nt = 0; nt < 4; ++nt) {
                const int r = brow + nt * 16;
                bf[nt] = *(const short8*)(curB + r * 64 + (((kc * 4 + quad) ^ (r & 7)) * 8));
            }
            #pragma unroll
            for (int mt = 0; mt < 8; ++mt) {
                const int r = arow + mt * 16;
                const short8 af = *(const short8*)(curA + r * 64 + (((kc * 4 + quad) ^ (r & 7)) * 8));
                #pragma unroll
                for (int nt = 0; nt < 4; ++nt) {
                    if (SWAP)
                        acc[mt][nt] = __builtin_amdgcn_mfma_f32_16x16x32_bf16(bf[nt], af, acc[mt][nt], 0, 0, 0);
                    else
                        acc[mt][nt] = __builtin_amdgcn_mfma_f32_16x16x32_bf16(af, bf[nt], acc[mt][nt], 0, 0, 0);
                }
            }
        }
        __builtin_amdgcn_s_setprio(0);

        if (t + 2 < 16) {
            WAITL0_BAR();                       // all waves done reading buf(t&1)
            const int k0 = (t + 2) * 64;
            #pragma unroll
            for (int i = 0; i < 4; ++i) {
                gl_lds16(pa[i] + k0, curA + loff[i]);
                gl_lds16(pb[i] + k0, curB + loff[i]);
            }
        }
    }
}

// QKV projections. z=0: Q -> [B,H,S,D] scaled by QSCALE (swapped, d-contig
// u16x4 stores). z=1: K -> [B,H,S,D] (swapped). z=2: V -> [B,H,D,S].
__global__ __launch_bounds__(512, 2)
void gemm_qkv(const ushort* __restrict__ Xq, const ushort* __restrict__ Xk,
              const ushort* __restrict__ Xv, const ushort* __restrict__ Wq,
              const ushort* __restrict__ Wk, const ushort* __restrict__ Wv,
              const float* __restrict__ bq, const float* __restrict__ bk,
              const float* __restrict__ bv, ushort* __restrict__ Qh,
              ushort* __restrict__ Kh, ushort* __restrict__ Vt)
{
    __shared__ ushort sh[65536];                   // 128 KB
    const int z = blockIdx.z;
    const ushort* X = (z == 0) ? Xq : (z == 1) ? Xk : Xv;
    const ushort* W = (z == 0) ? Wq : (z == 1) ? Wk : Wv;
    const float* bias = (z == 0) ? bq : (z == 1) ? bk : bv;
    ushort* dst = (z == 0) ? Qh : (z == 1) ? Kh : Vt;

    const int m0 = blockIdx.y * 256, n0 = blockIdx.x * 256;
    f32x4 acc[8][4];
    const int lane = threadIdx.x & 63, w = threadIdx.x >> 6;
    const int wm = w & 1, wn = w >> 1;
    const int l15 = lane & 15, quad = lane >> 4;

    if (z < 2) {
        qkv_core<1>(X, W, m0, n0, acc, sh);
        const float qsc = (z == 0) ? QSCALE : 1.0f;
        #pragma unroll
        for (int nt = 0; nt < 4; ++nt) {
            const int nb = n0 + wn * 64 + nt * 16 + quad * 4;   // feature dim
            const int h = nb >> 6, d0 = nb & 63;
            const float4 b4 = *(const float4*)(bias + nb);
            const float bb4[4] = {b4.x, b4.y, b4.z, b4.w};
            #pragma unroll
            for (int mt = 0; mt < 8; ++mt) {
                const int tok = m0 + wm * 128 + mt * 16 + l15;
                const int b = tok >> 11, s = tok & (S_ - 1);
                u16x4 pk;
                #pragma unroll
                for (int r = 0; r < 4; ++r)
                    pk[r] = f2bf((acc[mt][nt][r] + bb4[r]) * qsc);
                *(u16x4*)&dst[(((size_t)(b * H_ + h) * S_) + s) * D_ + d0] = pk;
            }
        }
    } else {
        qkv_core<0>(X, W, m0, n0, acc, sh);
        float bias4[4];
        #pragma unroll
        for (int nt = 0; nt < 4; ++nt)
            bias4[nt] = bias[n0 + wn * 64 + nt * 16 + l15];
        #pragma unroll
        for (int mt = 0; mt < 8; ++mt) {
            const int mrow0 = m0 + wm * 128 + mt * 16 + (quad * 4);
            const int b = mrow0 >> 11;
            const int s0 = mrow0 & (S_ - 1);
            #pragma unroll
            for (int nt = 0; nt < 4; ++nt) {
                const int n = n0 + wn * 64 + nt * 16 + l15;
                const int h = n >> 6, d = n & 63;
                u16x4 pk;
                #pragma unroll
                for (int r = 0; r < 4; ++r) pk[r] = f2bf(acc[mt][nt][r] + bias4[nt]);
                *(u16x4*)&Vt[(((size_t)(b * H_ + h) * D_) + d) * S_ + s0] = pk;
            }
        }
    }
}

// ---------------------------------------------------------------------------
// Final projection: out(fp32) = AO . Wo^T + bo.
// 128x64 tile (512 blocks = 2/CU).
// ---------------------------------------------------------------------------
__global__ __launch_bounds__(256)
void gemm_out(const ushort* __restrict__ X, const ushort* __restrict__ W,
              const float* __restrict__ bias, float* __restrict__ out)
{
    __shared__ ushort Ast[128 * 32];   // 8 KB
    __shared__ ushort Bst[64 * 32];    // 4 KB
    const int m0 = blockIdx.y * 128, n0 = blockIdx.x * 64;
    const int tid = threadIdx.x, lane = tid & 63, w = tid >> 6;
    const int wm = w & 1, wn = w >> 1;
    const int l15 = lane & 15, quad = lane >> 4;
    const int r0 = tid >> 2, c8 = (tid & 3) * 8;
    const int kb = quad * 8;

    const f32x4 zero = {0.f, 0.f, 0.f, 0.f};
    f32x4 acc[4][2];
    #pragma unroll
    for (int mt = 0; mt < 4; ++mt)
        #pragma unroll
        for (int nt = 0; nt < 2; ++nt) acc[mt][nt] = zero;

    for (int k0 = 0; k0 < K_; k0 += 32) {
        __syncthreads();
        const ushort* ga = X + (size_t)(m0 + r0) * K_ + k0 + c8;
        gl_lds16(ga, Ast + tid * 8);
        gl_lds16(ga + (size_t)64 * K_, Ast + 2048 + tid * 8);
        const ushort* gb = W + (size_t)(n0 + r0) * K_ + k0 + c8;
        gl_lds16(gb, Bst + tid * 8);
        __syncthreads();

        short8 af[4], bf[2];
        #pragma unroll
        for (int mt = 0; mt < 4; ++mt)
            af[mt] = *(const short8*)(Ast + (wm * 64 + mt * 16 + l15) * 32 + kb);
        #pragma unroll
        for (int nt = 0; nt < 2; ++nt)
            bf[nt] = *(const short8*)(Bst + (wn * 32 + nt * 16 + l15) * 32 + kb);
        #pragma unroll
        for (int mt = 0; mt < 4; ++mt)
            #pragma unroll
            for (int nt = 0; nt < 2; ++nt)
                acc[mt][nt] = __builtin_amdgcn_mfma_f32_16x16x32_bf16(af[mt], bf[nt], acc[mt][nt], 0, 0, 0);
    }

    float bias2[2];
    #pragma unroll
    for (int nt = 0; nt < 2; ++nt)
        bias2[nt] = bias[n0 + wn * 32 + nt * 16 + l15];

    #pragma unroll
    for (int mt = 0; mt < 4; ++mt) {
        const int mrow0 = m0 + wm * 64 + mt * 16 + quad * 4;
        #pragma unroll
        for (int nt = 0; nt < 2; ++nt) {
            const int n = n0 + wn * 32 + nt * 16 + l15;
            #pragma unroll
            for (int r = 0; r < 4; ++r)
                out[(size_t)(mrow0 + r) * E_ + n] = acc[mt][nt][r] + bias2[nt];
        }
    }
}

// ---------------------------------------------------------------------------
// Flash attention R7: R6's q-split QBLK=128 structure, with
//  (a) V read DIRECT from global (L1/L2-served: each V row's 64-col tile
//      span = one 128B line; per-block fetch == tile size). V staging,
//      its LDS traffic and conflicts removed. Register double-buffer:
//      prefetch V(j+1) during tile j (compiler auto-waits on reg use).
//  (b) bf16 pack via v_cvt_pk_bf16_f32 (2 ops vs ~10 int ops per 4 scores).
// LDS 33.3 KB: Qs(16K) + 2 K slots (8K each); K staged 2 ahead.
// vmcnt ledger (steady state at FL_SYNC of tile j):
//   K(j+1) x2 + V(j) x8 = 10 in flight -> FL_SYNC(10); K(j) retired
//   (in-order vmcnt retire: K(j) older than V(j-1), which PV(j-1) waited).
// Prologue: Q(4) K0(2) K1(2) V0(8) = 16; FL_SYNC(10) drains Q+K0 exactly.
// Tail: tile 30 no stage; tile 31 FL_SYNC(8) (V31 only in flight).
// Spill guard: WRITE_SIZE == 8192 KB (scratch ops would also corrupt the
// vmcnt ledger -> treat any growth as both perf and correctness alarm).
// ---------------------------------------------------------------------------
#define NTILE (S_ / 64)
#define QBLK 128

__device__ __forceinline__ void flash_stageK(const ushort* __restrict__ Kg,
                                             size_t qk_off, ushort* sh, int j,
                                             int row0, int gcol0, int row1, int gcol1,
                                             int chunk0, int chunk1, int lane)
{
    ushort* sb = sh + 8192 + (j & 1) * 4096;
    const int j0n = j * 64;
    gl_lds16(Kg + qk_off + (size_t)(j0n + row0) * D_ + gcol0 * 8, sb + chunk0 * 512 + lane * 8);
    gl_lds16(Kg + qk_off + (size_t)(j0n + row1) * D_ + gcol1 * 8, sb + chunk1 * 512 + lane * 8);
}

__device__ __forceinline__ void flash_ldK(const ushort* Kslot, int kvb, int l15, int quad,
                                          short8* ka)
{
    const int x7 = l15 & 7;
    const int rowA = (kvb + l15) * 64, rowB = (kvb + 16 + l15) * 64;
    ka[0] = *(const short8*)&Kslot[rowA + ((quad ^ x7) * 8)];
    ka[1] = *(const short8*)&Kslot[rowA + (((4 + quad) ^ x7) * 8)];
    ka[2] = *(const short8*)&Kslot[rowB + ((quad ^ x7) * 8)];
    ka[3] = *(const short8*)&Kslot[rowB + (((4 + quad) ^ x7) * 8)];
}

// V(j) direct loads: vb0 = Vg + vt_off + l15*S + cA; row nt adds nt*16*S.
__device__ __forceinline__ void flash_ldV(const ushort* vb0, int joff,
                                          uint2* vvA, uint2* vvB)
{
    #pragma unroll
    for (int nt = 0; nt < 4; ++nt) {
        vvA[nt] = *(const uint2*)(vb0 + (size_t)nt * 16 * S_ + joff);
        vvB[nt] = *(const uint2*)(vb0 + (size_t)nt * 16 * S_ + joff + 16);
    }
}

__device__ __forceinline__ void flash_qkpv(const short8* ka, const ushort* Qs,
                                           int qh, int l15, int quad,
                                           const uint2* vvA, const uint2* vvB,
                                           float* lsum, f32x4 o[4][4])
{
    const int x7 = l15 & 7;
    const f32x4 zero = {0.f, 0.f, 0.f, 0.f};
    short8 pa8[4];
    #pragma unroll
    for (int g = 0; g < 4; ++g) {
        const int qr = (qh + g * 16 + l15) * 64;
        const short8 qg0 = *(const short8*)&Qs[qr + ((quad ^ x7) * 8)];
        const short8 qg1 = *(const short8*)&Qs[qr + (((4 + quad) ^ x7) * 8)];
        f32x4 t = __builtin_amdgcn_mfma_f32_16x16x32_bf16(ka[0], qg0, zero, 0, 0, 0);
        t = __builtin_amdgcn_mfma_f32_16x16x32_bf16(ka[1], qg1, t, 0, 0, 0);
        f32x4 u = __builtin_amdgcn_mfma_f32_16x16x32_bf16(ka[2], qg0, zero, 0, 0, 0);
        u = __builtin_amdgcn_mfma_f32_16x16x32_bf16(ka[3], qg1, u, 0, 0, 0);
        const float p0 = EXP2F(t[0]), p1 = EXP2F(t[1]);
        const float p2 = EXP2F(t[2]), p3 = EXP2F(t[3]);
        const float r0 = EXP2F(u[0]), r1 = EXP2F(u[1]);
        const float r2 = EXP2F(u[2]), r3 = EXP2F(u[3]);
        lsum[g] += ((p0 + p1) + (p2 + p3)) + ((r0 + r1) + (r2 + r3));
        u32x4 pk;
        pk[0] = cvtpk(p0, p1);
        pk[1] = cvtpk(p2, p3);
        pk[2] = cvtpk(r0, r1);
        pk[3] = cvtpk(r2, r3);
        pa8[g] = __builtin_bit_cast(short8, pk);
    }
    #pragma unroll
    for (int nt = 0; nt < 4; ++nt) {
        u32x4 vk;
        vk[0] = vvA[nt].x; vk[1] = vvA[nt].y;
        vk[2] = vvB[nt].x; vk[3] = vvB[nt].y;
        const short8 vb8 = __builtin_bit_cast(short8, vk);
        #pragma unroll
        for (int g = 0; g < 4; ++g)
            o[g][nt] = __builtin_amdgcn_mfma_f32_16x16x32_bf16(pa8[g], vb8, o[g][nt], 0, 0, 0);
    }
}

__global__ __launch_bounds__(256, 2)
void flash_mfma(const ushort* __restrict__ Qg, const ushort* __restrict__ Kg,
                const ushort* __restrict__ Vg, ushort* __restrict__ AO)
{
    // 33.28 KB: Qs 8192 u (128x64) | K slot r at 8192 + r*4096 (64x64 each)
    __shared__ ushort sh[16640];
    ushort* Qs = sh;

    const int tid = threadIdx.x, lane = tid & 63, w = tid >> 6;
    const int l15 = lane & 15, quad = lane >> 4;
    const int q0 = blockIdx.x * QBLK, h = blockIdx.y, b = blockIdx.z;
    const size_t qk_off = (size_t)(b * H_ + h) * S_ * D_;   // [s][d]
    const size_t vt_off = (size_t)(b * H_ + h) * D_ * S_;   // [d][s]

    const int chunk0 = w, chunk1 = w + 4;
    const int row0 = chunk0 * 8 + (lane >> 3);
    const int row1 = chunk1 * 8 + (lane >> 3);
    const int gcol0 = (lane & 7) ^ (row0 & 7);
    const int gcol1 = (lane & 7) ^ (row1 & 7);

    const int qh  = (w >> 1) * 64;         // q-half base
    const int kvb = (w & 1) * 32;          // kv-half base within tile
    // V direct-read column base (de-swizzled from R6's LDS mapping)
    const int cA = ((w & 1) * 4 + (quad >> 1)) * 8 + (quad & 1) * 4;
    const ushort* vb0 = Vg + vt_off + (size_t)l15 * S_ + cA;

    // ---- prologue: Q (4 ops), K tiles 0,1 (2 ops each), V0 prefetch (8) ----
    #pragma unroll
    for (int i = 0; i < 4; ++i) {
        const int qc = w + i * 4;                  // 16 chunks of 8 rows
        const int qrow = qc * 8 + (lane >> 3);
        const int qg = (lane & 7) ^ (qrow & 7);
        gl_lds16(Qg + qk_off + (size_t)(q0 + qrow) * D_ + qg * 8,
                 Qs + qc * 512 + lane * 8);
    }
    flash_stageK(Kg, qk_off, sh, 0, row0, gcol0, row1, gcol1, chunk0, chunk1, lane);
    flash_stageK(Kg, qk_off, sh, 1, row0, gcol0, row1, gcol1, chunk0, chunk1, lane);
    uint2 vA0[4], vB0[4], vA1[4], vB1[4];
    flash_ldV(vb0, 0, vA0, vB0);               // V tile 0 -> set0

    f32x4 o[4][4];
    #pragma unroll
    for (int g = 0; g < 4; ++g)
        #pragma unroll
        for (int nt = 0; nt < 4; ++nt) o[g][nt] = {0.f, 0.f, 0.f, 0.f};
    float lsum[4] = {0.f, 0.f, 0.f, 0.f};

    const ushort* slot0 = sh + 8192;
    const ushort* slot1 = sh + 12288;
    short8 ka[4];

    for (int p = 0; p < 15; ++p) {
        const int jA = 2 * p;
        // ===== tile jA (even): slot0, V set0; prefetch V(jA+1) -> set1 =====
        FL_SYNC(10);                   // K(jA) landed (ledger in header)
        flash_ldK(slot0, kvb, l15, quad, ka);
        WAITL0_BAR();                  // all waves done reading slot0
        flash_stageK(Kg, qk_off, sh, jA + 2, row0, gcol0, row1, gcol1, chunk0, chunk1, lane);
        flash_ldV(vb0, (jA + 1) * 64, vA1, vB1);
        flash_qkpv(ka, Qs, qh, l15, quad, vA0, vB0, lsum, o);
        // ===== tile jA+1 (odd): slot1, V set1; prefetch V(jA+2) -> set0 =====
        FL_SYNC(10);
        flash_ldK(slot1, kvb, l15, quad, ka);
        WAITL0_BAR();
        flash_stageK(Kg, qk_off, sh, jA + 3, row0, gcol0, row1, gcol1, chunk0, chunk1, lane);
        flash_ldV(vb0, (jA + 2) * 64, vA0, vB0);
        flash_qkpv(ka, Qs, qh, l15, quad, vA1, vB1, lsum, o);
    }

    // ===== peeled tail: tiles 30, 31 =====
    FL_SYNC(10);                       // K(30) landed; K31(2)+V30(8) in flight
    flash_ldK(slot0, kvb, l15, quad, ka);
    flash_ldV(vb0, 31 * 64, vA1, vB1); // prefetch V31 (no stage, no lds-bar)
    flash_qkpv(ka, Qs, qh, l15, quad, vA0, vB0, lsum, o);
    FL_SYNC(8);                        // V31 only in flight; K31 retired
    flash_ldK(slot1, kvb, l15, quad, ka);
    flash_qkpv(ka, Qs, qh, l15, quad, vA1, vB1, lsum, o);

    // ---- reduction: intra-wave over quads, then 2-way with partner w^1 ----
    #pragma unroll
    for (int g = 0; g < 4; ++g) {
        lsum[g] += __shfl_xor(lsum[g], 16);
        lsum[g] += __shfl_xor(lsum[g], 32);   // now quad-uniform
    }
    __syncthreads();
    float* fb = (float*)sh;                   // 8320 floats available
    if (w & 1) {                              // waves 1,3 export
        #pragma unroll
        for (int g = 0; g < 4; ++g) {
            #pragma unroll
            for (int nt = 0; nt < 4; ++nt)
                #pragma unroll
                for (int r = 0; r < 4; ++r)
                    fb[(w >> 1) * 4096 + g * 1024 + (nt * 4 + r) * 64 + lane] = o[g][nt][r];
            if (quad == 0) fb[8192 + (w >> 1) * 64 + g * 16 + l15] = lsum[g];
        }
    }
    __syncthreads();
    if (!(w & 1)) {                           // waves 0,2 merge + store
        #pragma unroll
        for (int g = 0; g < 4; ++g) {
            #pragma unroll
            for (int nt = 0; nt < 4; ++nt)
                #pragma unroll
                for (int r = 0; r < 4; ++r)
                    o[g][nt][r] += fb[(w >> 1) * 4096 + g * 1024 + (nt * 4 + r) * 64 + lane];
            lsum[g] += fb[8192 + (w >> 1) * 64 + g * 16 + l15];
        }
        #pragma unroll
        for (int g = 0; g < 4; ++g) {
            const float inv = 1.0f / lsum[g];     // q = qh + g*16 + l15
            float invr[4];
            #pragma unroll
            for (int r = 0; r < 4; ++r)
                invr[r] = __shfl(inv, (lane & 0x30) | (quad * 4 + r));
            #pragma unroll
            for (int nt = 0; nt < 4; ++nt) {
                const int e = h * 64 + nt * 16 + l15;
                #pragma unroll
                for (int r = 0; r < 4; ++r) {
                    const int s = q0 + qh + g * 16 + quad * 4 + r;
                    AO[(size_t)(b * S_ + s) * E_ + e] = f2bf(o[g][nt][r] * invr[r]);
                }
            }
        }
    }
}

// ---------------------------------------------------------------------------
extern "C" void kernel_launch(void* const* d_in, const int* in_sizes, int n_in,
                              void* d_out, int out_size, void* d_ws, size_t ws_size,
                              hipStream_t stream) {
    const float* query = (const float*)d_in[0];
    const float* key   = (const float*)d_in[1];
    const float* value = (const float*)d_in[2];
    const float* Wq = (const float*)d_in[3];
    const float* bq = (const float*)d_in[4];
    const float* Wk = (const float*)d_in[5];
    const float* bk = (const float*)d_in[6];
    const float* Wv = (const float*)d_in[7];
    const float* bv = (const float*)d_in[8];
    const float* Wo = (const float*)d_in[9];
    const float* bo = (const float*)d_in[10];
    float* out = (float*)d_out;

    ushort* ws = (ushort*)d_ws;
    ushort* Xq  = ws;
    ushort* Xk  = ws + 4194304u;
    ushort* Xv  = ws + 8388608u;
    ushort* Wqb = ws + 12582912u;
    ushort* Wkb = ws + 13631488u;
    ushort* Wvb = ws + 14680064u;
    ushort* Wob = ws + 15728640u;
    ushort* Qh  = ws + 16777216u;          // [B,H,S,D] (pre-scaled by QSCALE)
    ushort* Kh  = ws + 20971520u;          // [B,H,S,D]
    ushort* Vt  = ws + 25165824u;          // [B,H,D,S]
    ushort* AO  = ws + 29360128u;          // [B,S,E]

    cvt_all<<<8192, 256, 0, stream>>>(query, key, value, Wq, Wk, Wv, Wo, ws);
    gemm_qkv<<<dim3(4, 16, 3), 512, 0, stream>>>(Xq, Xk, Xv, Wqb, Wkb, Wvb,
                                                 bq, bk, bv, Qh, Kh, Vt);
    flash_mfma<<<dim3(S_ / QBLK, H_, B_), 256, 0, stream>>>(Qh, Kh, Vt, AO);
    gemm_out<<<dim3(16, 32), 256, 0, stream>>>(AO, Wob, bo, out);
}

// Round 8
// 220.575 us; speedup vs baseline: 1.1061x; 1.1061x over previous
//
#include <hip/hip_runtime.h>

#define B_ 2
#define S_ 2048
#define E_ 1024
#define H_ 16
#define D_ 64
#define M_ (B_*S_)
#define K_ E_

typedef __attribute__((ext_vector_type(8))) short  short8;
typedef __attribute__((ext_vector_type(4))) float  f32x4;
typedef __attribute__((ext_vector_type(8))) unsigned short u16x8;
typedef __attribute__((ext_vector_type(4))) unsigned short u16x4;
typedef __attribute__((ext_vector_type(4))) unsigned int   u32x4;

// 0.125 * log2(e): folded into Q so scores arrive in exp2 domain
#define QSCALE 0.18033688011112042f

#if __has_builtin(__builtin_amdgcn_exp2f)
#define EXP2F(x) __builtin_amdgcn_exp2f(x)   // raw v_exp_f32
#else
#define EXP2F(x) exp2f(x)
#endif

__device__ __forceinline__ unsigned short f2bf(float f) {   // RNE
    unsigned u = __float_as_uint(f);
    u += 0x7fffu + ((u >> 16) & 1u);
    return (unsigned short)(u >> 16);
}

// 2x f32 -> packed bf16 in one instruction (lo=a, hi=b), RNE.
// R7 verified: passed with absmax 0.00049 unchanged; VALUBusy -18 points.
__device__ __forceinline__ unsigned cvtpk(float a, float b) {
    unsigned r;
    asm("v_cvt_pk_bf16_f32 %0, %1, %2" : "=v"(r) : "v"(a), "v"(b));
    return r;
}

__device__ __forceinline__ void gl_lds16(const ushort* g, ushort* l) {
    __builtin_amdgcn_global_load_lds((const __attribute__((address_space(1))) void*)g,
                                     (__attribute__((address_space(3))) void*)l,
                                     16, 0, 0);
}

// counted-vmcnt barrier: wait for all but the newest N vmem ops, then raw
// s_barrier (no compiler vmcnt(0) drain -- the whole point).
#define FL_SYNC(N) do {                                                   \
    asm volatile("s_waitcnt vmcnt(" #N ")" ::: "memory");                 \
    __builtin_amdgcn_s_barrier();                                         \
    asm volatile("" ::: "memory");                                        \
} while (0)

#define WAITL0_BAR() do {                                                 \
    asm volatile("s_waitcnt lgkmcnt(0)" ::: "memory");                    \
    __builtin_amdgcn_s_barrier();                                         \
    asm volatile("" ::: "memory");                                        \
} while (0)

// ---------------------------------------------------------------------------
// fp32 -> bf16 conversion (all inputs).
// ---------------------------------------------------------------------------
__global__ __launch_bounds__(256)
void cvt_all(const float* __restrict__ q, const float* __restrict__ k,
             const float* __restrict__ v, const float* __restrict__ wq,
             const float* __restrict__ wk, const float* __restrict__ wv,
             const float* __restrict__ wo, ushort* __restrict__ dst)
{
    const int bid = blockIdx.x;
    const float* src;
    size_t dof;
    int local;
    if (bid < 6144) {
        const int t = bid >> 11;
        src = (t == 0) ? q : (t == 1) ? k : v;
        dof = (size_t)t * 4194304u;
        local = bid & 2047;
    } else {
        const int r = bid - 6144;
        const int t = r >> 9;
        src = (t == 0) ? wq : (t == 1) ? wk : (t == 2) ? wv : wo;
        dof = 12582912u + (size_t)t * 1048576u;
        local = r & 511;
    }
    const size_t idx = (size_t)local * 2048 + threadIdx.x * 8;
    const float4 a = *(const float4*)(src + idx);
    const float4 b = *(const float4*)(src + idx + 4);
    u16x8 o;
    o[0] = f2bf(a.x); o[1] = f2bf(a.y); o[2] = f2bf(a.z); o[3] = f2bf(a.w);
    o[4] = f2bf(b.x); o[5] = f2bf(b.y); o[6] = f2bf(b.z); o[7] = f2bf(b.w);
    *(u16x8*)(dst + dof + idx) = o;
}

// ---------------------------------------------------------------------------
// 256x256xBK64 pipelined GEMM core for the QKV projections (R3, kept).
// ---------------------------------------------------------------------------
template<int SWAP>
__device__ __forceinline__ void qkv_core(const ushort* __restrict__ X,
                                         const ushort* __restrict__ W,
                                         int m0, int n0,
                                         f32x4 acc[8][4], ushort* sh)
{
    const int tid  = threadIdx.x;
    const int lane = tid & 63;
    const int w    = tid >> 6;          // 0..7
    const int wm   = w & 1;             // 2 M-waves
    const int wn   = w >> 1;            // 4 N-waves
    const int l15  = lane & 15, quad = lane >> 4;

    const int srow = lane >> 3, schunk = lane & 7;
    const int scol = (schunk ^ srow) * 8;          // row&7 == srow
    const ushort* pa[4]; const ushort* pb[4]; int loff[4];
    #pragma unroll
    for (int i = 0; i < 4; ++i) {
        const int row = (w * 4 + i) * 8 + srow;
        pa[i] = X + (size_t)(m0 + row) * K_ + scol;
        pb[i] = W + (size_t)(n0 + row) * K_ + scol;
        loff[i] = (w * 4 + i) * 512 + lane * 8;
    }

    const f32x4 zero = {0.f, 0.f, 0.f, 0.f};
    #pragma unroll
    for (int mt = 0; mt < 8; ++mt)
        #pragma unroll
        for (int nt = 0; nt < 4; ++nt) acc[mt][nt] = zero;

    #pragma unroll
    for (int i = 0; i < 4; ++i) {
        gl_lds16(pa[i],      sh + loff[i]);
        gl_lds16(pb[i],      sh + 16384 + loff[i]);
    }
    #pragma unroll
    for (int i = 0; i < 4; ++i) {
        gl_lds16(pa[i] + 64, sh + 32768 + loff[i]);
        gl_lds16(pb[i] + 64, sh + 32768 + 16384 + loff[i]);
    }

    const int arow = wm * 128 + l15;               // + mt*16
    const int brow = wn * 64 + l15;                // + nt*16

    for (int t = 0; t < 16; ++t) {
        ushort* curA = sh + (t & 1) * 32768;
        ushort* curB = curA + 16384;

        if (t < 15) { FL_SYNC(8); } else { FL_SYNC(0); }

        __builtin_amdgcn_s_setprio(1);
        #pragma unroll
        for (int kc = 0; kc < 2; ++kc) {
            short8 bf[4];
            #pragma unroll
            for (int nt = 0; nt < 4; ++nt) {
                const int r = brow + nt * 16;
                bf[nt] = *(const short8*)(curB + r * 64 + (((kc * 4 + quad) ^ (r & 7)) * 8));
            }
            #pragma unroll
            for (int mt = 0; mt < 8; ++mt) {
                const int r = arow + mt * 16;
                const short8 af = *(const short8*)(curA + r * 64 + (((kc * 4 + quad) ^ (r & 7)) * 8));
                #pragma unroll
                for (int nt = 0; nt < 4; ++nt) {
                    if (SWAP)
                        acc[mt][nt] = __builtin_amdgcn_mfma_f32_16x16x32_bf16(bf[nt], af, acc[mt][nt], 0, 0, 0);
                    else
                        acc[mt][nt] = __builtin_amdgcn_mfma_f32_16x16x32_bf16(af, bf[nt], acc[mt][nt], 0, 0, 0);
                }
            }
        }
        __builtin_amdgcn_s_setprio(0);

        if (t + 2 < 16) {
            WAITL0_BAR();                       // all waves done reading buf(t&1)
            const int k0 = (t + 2) * 64;
            #pragma unroll
            for (int i = 0; i < 4; ++i) {
                gl_lds16(pa[i] + k0, curA + loff[i]);
                gl_lds16(pb[i] + k0, curB + loff[i]);
            }
        }
    }
}

// QKV projections. z=0: Q -> [B,H,S,D] scaled by QSCALE (swapped, d-contig
// u16x4 stores). z=1: K -> [B,H,S,D] (swapped). z=2: V -> [B,H,D,S].
__global__ __launch_bounds__(512, 2)
void gemm_qkv(const ushort* __restrict__ Xq, const ushort* __restrict__ Xk,
              const ushort* __restrict__ Xv, const ushort* __restrict__ Wq,
              const ushort* __restrict__ Wk, const ushort* __restrict__ Wv,
              const float* __restrict__ bq, const float* __restrict__ bk,
              const float* __restrict__ bv, ushort* __restrict__ Qh,
              ushort* __restrict__ Kh, ushort* __restrict__ Vt)
{
    __shared__ ushort sh[65536];                   // 128 KB
    const int z = blockIdx.z;
    const ushort* X = (z == 0) ? Xq : (z == 1) ? Xk : Xv;
    const ushort* W = (z == 0) ? Wq : (z == 1) ? Wk : Wv;
    const float* bias = (z == 0) ? bq : (z == 1) ? bk : bv;
    ushort* dst = (z == 0) ? Qh : (z == 1) ? Kh : Vt;

    const int m0 = blockIdx.y * 256, n0 = blockIdx.x * 256;
    f32x4 acc[8][4];
    const int lane = threadIdx.x & 63, w = threadIdx.x >> 6;
    const int wm = w & 1, wn = w >> 1;
    const int l15 = lane & 15, quad = lane >> 4;

    if (z < 2) {
        qkv_core<1>(X, W, m0, n0, acc, sh);
        const float qsc = (z == 0) ? QSCALE : 1.0f;
        #pragma unroll
        for (int nt = 0; nt < 4; ++nt) {
            const int nb = n0 + wn * 64 + nt * 16 + quad * 4;   // feature dim
            const int h = nb >> 6, d0 = nb & 63;
            const float4 b4 = *(const float4*)(bias + nb);
            const float bb4[4] = {b4.x, b4.y, b4.z, b4.w};
            #pragma unroll
            for (int mt = 0; mt < 8; ++mt) {
                const int tok = m0 + wm * 128 + mt * 16 + l15;
                const int b = tok >> 11, s = tok & (S_ - 1);
                u16x4 pk;
                #pragma unroll
                for (int r = 0; r < 4; ++r)
                    pk[r] = f2bf((acc[mt][nt][r] + bb4[r]) * qsc);
                *(u16x4*)&dst[(((size_t)(b * H_ + h) * S_) + s) * D_ + d0] = pk;
            }
        }
    } else {
        qkv_core<0>(X, W, m0, n0, acc, sh);
        float bias4[4];
        #pragma unroll
        for (int nt = 0; nt < 4; ++nt)
            bias4[nt] = bias[n0 + wn * 64 + nt * 16 + l15];
        #pragma unroll
        for (int mt = 0; mt < 8; ++mt) {
            const int mrow0 = m0 + wm * 128 + mt * 16 + (quad * 4);
            const int b = mrow0 >> 11;
            const int s0 = mrow0 & (S_ - 1);
            #pragma unroll
            for (int nt = 0; nt < 4; ++nt) {
                const int n = n0 + wn * 64 + nt * 16 + l15;
                const int h = n >> 6, d = n & 63;
                u16x4 pk;
                #pragma unroll
                for (int r = 0; r < 4; ++r) pk[r] = f2bf(acc[mt][nt][r] + bias4[nt]);
                *(u16x4*)&Vt[(((size_t)(b * H_ + h) * D_) + d) * S_ + s0] = pk;
            }
        }
    }
}

// ---------------------------------------------------------------------------
// Final projection: out(fp32) = AO . Wo^T + bo.
// 128x64 tile (512 blocks = 2/CU).
// ---------------------------------------------------------------------------
__global__ __launch_bounds__(256)
void gemm_out(const ushort* __restrict__ X, const ushort* __restrict__ W,
              const float* __restrict__ bias, float* __restrict__ out)
{
    __shared__ ushort Ast[128 * 32];   // 8 KB
    __shared__ ushort Bst[64 * 32];    // 4 KB
    const int m0 = blockIdx.y * 128, n0 = blockIdx.x * 64;
    const int tid = threadIdx.x, lane = tid & 63, w = tid >> 6;
    const int wm = w & 1, wn = w >> 1;
    const int l15 = lane & 15, quad = lane >> 4;
    const int r0 = tid >> 2, c8 = (tid & 3) * 8;
    const int kb = quad * 8;

    const f32x4 zero = {0.f, 0.f, 0.f, 0.f};
    f32x4 acc[4][2];
    #pragma unroll
    for (int mt = 0; mt < 4; ++mt)
        #pragma unroll
        for (int nt = 0; nt < 2; ++nt) acc[mt][nt] = zero;

    for (int k0 = 0; k0 < K_; k0 += 32) {
        __syncthreads();
        const ushort* ga = X + (size_t)(m0 + r0) * K_ + k0 + c8;
        gl_lds16(ga, Ast + tid * 8);
        gl_lds16(ga + (size_t)64 * K_, Ast + 2048 + tid * 8);
        const ushort* gb = W + (size_t)(n0 + r0) * K_ + k0 + c8;
        gl_lds16(gb, Bst + tid * 8);
        __syncthreads();

        short8 af[4], bf[2];
        #pragma unroll
        for (int mt = 0; mt < 4; ++mt)
            af[mt] = *(const short8*)(Ast + (wm * 64 + mt * 16 + l15) * 32 + kb);
        #pragma unroll
        for (int nt = 0; nt < 2; ++nt)
            bf[nt] = *(const short8*)(Bst + (wn * 32 + nt * 16 + l15) * 32 + kb);
        #pragma unroll
        for (int mt = 0; mt < 4; ++mt)
            #pragma unroll
            for (int nt = 0; nt < 2; ++nt)
                acc[mt][nt] = __builtin_amdgcn_mfma_f32_16x16x32_bf16(af[mt], bf[nt], acc[mt][nt], 0, 0, 0);
    }

    float bias2[2];
    #pragma unroll
    for (int nt = 0; nt < 2; ++nt)
        bias2[nt] = bias[n0 + wn * 32 + nt * 16 + l15];

    #pragma unroll
    for (int mt = 0; mt < 4; ++mt) {
        const int mrow0 = m0 + wm * 64 + mt * 16 + quad * 4;
        #pragma unroll
        for (int nt = 0; nt < 2; ++nt) {
            const int n = n0 + wn * 32 + nt * 16 + l15;
            #pragma unroll
            for (int r = 0; r < 4; ++r)
                out[(size_t)(mrow0 + r) * E_ + n] = acc[mt][nt][r] + bias2[nt];
        }
    }
}

// ---------------------------------------------------------------------------
// Flash attention R8: R6's verified structure (q-split QBLK=128, V staged
// in LDS, 2-slot ring, counted vmcnt) + cvt_pk bf16 pack (the good half of
// R7: VALUBusy -18pts, numerics verified). V direct-from-global REVERTED:
// R7 showed the scatter shape (8B/lane across 16 lines 4KB apart) costs
// more than staging saves, despite full L2 residency.
// Spill guard: WRITE_SIZE == 8192 KB.
// ---------------------------------------------------------------------------
#define NTILE (S_ / 64)
#define QBLK 128

__device__ __forceinline__ void flash_stage(const ushort* __restrict__ Kg,
                                            const ushort* __restrict__ Vg,
                                            size_t qk_off, size_t vt_off,
                                            ushort* sh, int j,
                                            int row0, int gcol0, int row1, int gcol1,
                                            int chunk0, int chunk1, int lane)
{
    ushort* sb = sh + 8192 + (j & 1) * 8192;
    const int j0n = j * 64;
    gl_lds16(Kg + qk_off + (size_t)(j0n + row0) * D_ + gcol0 * 8, sb + chunk0 * 512 + lane * 8);
    gl_lds16(Vg + vt_off + (size_t)row0 * S_ + j0n + gcol0 * 8, sb + 4096 + chunk0 * 512 + lane * 8);
    gl_lds16(Kg + qk_off + (size_t)(j0n + row1) * D_ + gcol1 * 8, sb + chunk1 * 512 + lane * 8);
    gl_lds16(Vg + vt_off + (size_t)row1 * S_ + j0n + gcol1 * 8, sb + 4096 + chunk1 * 512 + lane * 8);
}

__global__ __launch_bounds__(256, 2)
void flash_mfma(const ushort* __restrict__ Qg, const ushort* __restrict__ Kg,
                const ushort* __restrict__ Vg, ushort* __restrict__ AO)
{
    // 48 KB: Qs(8192 u = 128x64) | slot r at 8192 + r*8192: K(4096 u), V(4096 u)
    __shared__ ushort sh[24576];
    ushort* Qs = sh;

    const int tid = threadIdx.x, lane = tid & 63, w = tid >> 6;
    const int l15 = lane & 15, quad = lane >> 4;
    const int q0 = blockIdx.x * QBLK, h = blockIdx.y, b = blockIdx.z;
    const size_t qk_off = (size_t)(b * H_ + h) * S_ * D_;   // [s][d]
    const size_t vt_off = (size_t)(b * H_ + h) * D_ * S_;   // [d][s]

    const int chunk0 = w, chunk1 = w + 4;
    const int row0 = chunk0 * 8 + (lane >> 3);
    const int row1 = chunk1 * 8 + (lane >> 3);
    const int gcol0 = (lane & 7) ^ (row0 & 7);
    const int gcol1 = (lane & 7) ^ (row1 & 7);

    // prologue: Q (4 ops, 128 rows), then K/V tiles 0,1 (4 ops each)
    #pragma unroll
    for (int i = 0; i < 4; ++i) {
        const int qc = w + i * 4;                  // 16 chunks of 8 rows
        const int qrow = qc * 8 + (lane >> 3);
        const int qg = (lane & 7) ^ (qrow & 7);
        gl_lds16(Qg + qk_off + (size_t)(q0 + qrow) * D_ + qg * 8,
                 Qs + qc * 512 + lane * 8);
    }
    flash_stage(Kg, Vg, qk_off, vt_off, sh, 0, row0, gcol0, row1, gcol1, chunk0, chunk1, lane);
    flash_stage(Kg, Vg, qk_off, vt_off, sh, 1, row0, gcol0, row1, gcol1, chunk0, chunk1, lane);

    FL_SYNC(8);                        // Q landed (tiles 0,1 = 8 ops in flight)

    f32x4 o[4][4];                     // o[g][nt]: O[q=qh+g*16+quad*4+r][d=nt*16+l15]
    #pragma unroll
    for (int g = 0; g < 4; ++g)
        #pragma unroll
        for (int nt = 0; nt < 4; ++nt) o[g][nt] = {0.f, 0.f, 0.f, 0.f};
    float lsum[4] = {0.f, 0.f, 0.f, 0.f};  // partial denom, q = qh + g*16 + l15

    const int qh  = (w >> 1) * 64;         // q-half base
    const int kvb = (w & 1) * 32;          // kv-half base within tile
    const int x7  = l15 & 7;
    const int rowA = (kvb + l15) * 64;          // K rows, group A (kv 16-group 0)
    const int rowB = (kvb + 16 + l15) * 64;     // group B
    const int gA = ((w & 1) * 4 + (quad >> 1)) ^ x7;        // V col-group, A
    const int gB = ((w & 1) * 4 + 2 + (quad >> 1)) ^ x7;    // B
    const f32x4 zero = {0.f, 0.f, 0.f, 0.f};

    for (int j = 0; j < NTILE; ++j) {
        const ushort* Kb = sh + 8192 + (j & 1) * 8192;
        const ushort* Vb = Kb + 4096;
        if (j < NTILE - 1) { FL_SYNC(4); } else { FL_SYNC(0); }

        // K frags (both kv-16-groups of this wave's half) + V frags
        const short8 ka0 = *(const short8*)&Kb[rowA + ((quad ^ x7) * 8)];
        const short8 ka1 = *(const short8*)&Kb[rowA + (((4 + quad) ^ x7) * 8)];
        const short8 ka2 = *(const short8*)&Kb[rowB + ((quad ^ x7) * 8)];
        const short8 ka3 = *(const short8*)&Kb[rowB + (((4 + quad) ^ x7) * 8)];
        uint2 vvA[4], vvB[4];
        #pragma unroll
        for (int nt = 0; nt < 4; ++nt) {
            vvA[nt] = *(const uint2*)&Vb[(nt * 16 + l15) * 64 + gA * 8 + (quad & 1) * 4];
            vvB[nt] = *(const uint2*)&Vb[(nt * 16 + l15) * 64 + gB * 8 + (quad & 1) * 4];
        }

        // QK both groups + exp2 + cvt_pk pack; Q frags from LDS
        uint2 paLo[4], paHi[4];
        #pragma unroll
        for (int g = 0; g < 4; ++g) {
            const int qr = (qh + g * 16 + l15) * 64;
            const short8 qg0 = *(const short8*)&Qs[qr + ((quad ^ x7) * 8)];
            const short8 qg1 = *(const short8*)&Qs[qr + (((4 + quad) ^ x7) * 8)];
            f32x4 t = __builtin_amdgcn_mfma_f32_16x16x32_bf16(ka0, qg0, zero, 0, 0, 0);
            t = __builtin_amdgcn_mfma_f32_16x16x32_bf16(ka1, qg1, t, 0, 0, 0);
            f32x4 u = __builtin_amdgcn_mfma_f32_16x16x32_bf16(ka2, qg0, zero, 0, 0, 0);
            u = __builtin_amdgcn_mfma_f32_16x16x32_bf16(ka3, qg1, u, 0, 0, 0);
            {
                const float p0 = EXP2F(t[0]), p1 = EXP2F(t[1]);
                const float p2 = EXP2F(t[2]), p3 = EXP2F(t[3]);
                lsum[g] += (p0 + p1) + (p2 + p3);
                paLo[g].x = cvtpk(p0, p1);
                paLo[g].y = cvtpk(p2, p3);
            }
            {
                const float p0 = EXP2F(u[0]), p1 = EXP2F(u[1]);
                const float p2 = EXP2F(u[2]), p3 = EXP2F(u[3]);
                lsum[g] += (p0 + p1) + (p2 + p3);
                paHi[g].x = cvtpk(p0, p1);
                paHi[g].y = cvtpk(p2, p3);
            }
        }

        // PV at full K=32: A-frag = {groupA p (slots 0..3), groupB p (4..7)}
        short8 pa8[4];
        #pragma unroll
        for (int g = 0; g < 4; ++g) {
            u32x4 pk;
            pk[0] = paLo[g].x; pk[1] = paLo[g].y;
            pk[2] = paHi[g].x; pk[3] = paHi[g].y;
            pa8[g] = __builtin_bit_cast(short8, pk);
        }
        #pragma unroll
        for (int nt = 0; nt < 4; ++nt) {
            u32x4 vk;
            vk[0] = vvA[nt].x; vk[1] = vvA[nt].y;
            vk[2] = vvB[nt].x; vk[3] = vvB[nt].y;
            const short8 vb8 = __builtin_bit_cast(short8, vk);
            #pragma unroll
            for (int g = 0; g < 4; ++g)
                o[g][nt] = __builtin_amdgcn_mfma_f32_16x16x32_bf16(pa8[g], vb8, o[g][nt], 0, 0, 0);
        }

        // stage tile j+2 into the slot just consumed (after all waves' reads)
        if (j < NTILE - 2) {
            WAITL0_BAR();
            flash_stage(Kg, Vg, qk_off, vt_off, sh, j + 2,
                        row0, gcol0, row1, gcol1, chunk0, chunk1, lane);
        }
    }

    // ---- reduction: intra-wave over quads, then 2-way with partner w^1 ----
    #pragma unroll
    for (int g = 0; g < 4; ++g) {
        lsum[g] += __shfl_xor(lsum[g], 16);
        lsum[g] += __shfl_xor(lsum[g], 32);   // now quad-uniform
    }
    __syncthreads();
    float* fb = (float*)sh;                   // 12288 floats available
    if (w & 1) {                              // waves 1,3 export
        #pragma unroll
        for (int g = 0; g < 4; ++g) {
            #pragma unroll
            for (int nt = 0; nt < 4; ++nt)
                #pragma unroll
                for (int r = 0; r < 4; ++r)
                    fb[(w >> 1) * 4096 + g * 1024 + (nt * 4 + r) * 64 + lane] = o[g][nt][r];
            if (quad == 0) fb[8192 + (w >> 1) * 64 + g * 16 + l15] = lsum[g];
        }
    }
    __syncthreads();
    if (!(w & 1)) {                           // waves 0,2 merge + store
        #pragma unroll
        for (int g = 0; g < 4; ++g) {
            #pragma unroll
            for (int nt = 0; nt < 4; ++nt)
                #pragma unroll
                for (int r = 0; r < 4; ++r)
                    o[g][nt][r] += fb[(w >> 1) * 4096 + g * 1024 + (nt * 4 + r) * 64 + lane];
            lsum[g] += fb[8192 + (w >> 1) * 64 + g * 16 + l15];
        }
        #pragma unroll
        for (int g = 0; g < 4; ++g) {
            const float inv = 1.0f / lsum[g];     // q = qh + g*16 + l15
            float invr[4];
            #pragma unroll
            for (int r = 0; r < 4; ++r)
                invr[r] = __shfl(inv, (lane & 0x30) | (quad * 4 + r));
            #pragma unroll
            for (int nt = 0; nt < 4; ++nt) {
                const int e = h * 64 + nt * 16 + l15;
                #pragma unroll
                for (int r = 0; r < 4; ++r) {
                    const int s = q0 + qh + g * 16 + quad * 4 + r;
                    AO[(size_t)(b * S_ + s) * E_ + e] = f2bf(o[g][nt][r] * invr[r]);
                }
            }
        }
    }
}

// ---------------------------------------------------------------------------
extern "C" void kernel_launch(void* const* d_in, const int* in_sizes, int n_in,
                              void* d_out, int out_size, void* d_ws, size_t ws_size,
                              hipStream_t stream) {
    const float* query = (const float*)d_in[0];
    const float* key   = (const float*)d_in[1];
    const float* value = (const float*)d_in[2];
    const float* Wq = (const float*)d_in[3];
    const float* bq = (const float*)d_in[4];
    const float* Wk = (const float*)d_in[5];
    const float* bk = (const float*)d_in[6];
    const float* Wv = (const float*)d_in[7];
    const float* bv = (const float*)d_in[8];
    const float* Wo = (const float*)d_in[9];
    const float* bo = (const float*)d_in[10];
    float* out = (float*)d_out;

    ushort* ws = (ushort*)d_ws;
    ushort* Xq  = ws;
    ushort* Xk  = ws + 4194304u;
    ushort* Xv  = ws + 8388608u;
    ushort* Wqb = ws + 12582912u;
    ushort* Wkb = ws + 13631488u;
    ushort* Wvb = ws + 14680064u;
    ushort* Wob = ws + 15728640u;
    ushort* Qh  = ws + 16777216u;          // [B,H,S,D] (pre-scaled by QSCALE)
    ushort* Kh  = ws + 20971520u;          // [B,H,S,D]
    ushort* Vt  = ws + 25165824u;          // [B,H,D,S]
    ushort* AO  = ws + 29360128u;          // [B,S,E]

    cvt_all<<<8192, 256, 0, stream>>>(query, key, value, Wq, Wk, Wv, Wo, ws);
    gemm_qkv<<<dim3(4, 16, 3), 512, 0, stream>>>(Xq, Xk, Xv, Wqb, Wkb, Wvb,
                                                 bq, bk, bv, Qh, Kh, Vt);
    flash_mfma<<<dim3(S_ / QBLK, H_, B_), 256, 0, stream>>>(Qh, Kh, Vt, AO);
    gemm_out<<<dim3(16, 32), 256, 0, stream>>>(AO, Wob, bo, out);
}

// Round 9
// 215.662 us; speedup vs baseline: 1.1313x; 1.0228x over previous
//
#include <hip/hip_runtime.h>

#define B_ 2
#define S_ 2048
#define E_ 1024
#define H_ 16
#define D_ 64
#define M_ (B_*S_)
#define K_ E_

typedef __attribute__((ext_vector_type(8))) short  short8;
typedef __attribute__((ext_vector_type(4))) float  f32x4;
typedef __attribute__((ext_vector_type(8))) unsigned short u16x8;
typedef __attribute__((ext_vector_type(4))) unsigned short u16x4;
typedef __attribute__((ext_vector_type(4))) unsigned int   u32x4;

// 0.125 * log2(e): folded into Q so scores arrive in exp2 domain
#define QSCALE 0.18033688011112042f

#if __has_builtin(__builtin_amdgcn_exp2f)
#define EXP2F(x) __builtin_amdgcn_exp2f(x)   // raw v_exp_f32
#else
#define EXP2F(x) exp2f(x)
#endif

__device__ __forceinline__ unsigned short f2bf(float f) {   // RNE
    unsigned u = __float_as_uint(f);
    u += 0x7fffu + ((u >> 16) & 1u);
    return (unsigned short)(u >> 16);
}

// 2x f32 -> packed bf16 in one instruction (lo=a, hi=b), RNE.
// R8 verified: -5.1us on flash, absmax unchanged.
__device__ __forceinline__ unsigned cvtpk(float a, float b) {
    unsigned r;
    asm("v_cvt_pk_bf16_f32 %0, %1, %2" : "=v"(r) : "v"(a), "v"(b));
    return r;
}

__device__ __forceinline__ void gl_lds16(const ushort* g, ushort* l) {
    __builtin_amdgcn_global_load_lds((const __attribute__((address_space(1))) void*)g,
                                     (__attribute__((address_space(3))) void*)l,
                                     16, 0, 0);
}

// counted-vmcnt barrier: wait for all but the newest N vmem ops, then raw
// s_barrier (no compiler vmcnt(0) drain -- the whole point).
#define FL_SYNC(N) do {                                                   \
    asm volatile("s_waitcnt vmcnt(" #N ")" ::: "memory");                 \
    __builtin_amdgcn_s_barrier();                                         \
    asm volatile("" ::: "memory");                                        \
} while (0)

#define WAITL0_BAR() do {                                                 \
    asm volatile("s_waitcnt lgkmcnt(0)" ::: "memory");                    \
    __builtin_amdgcn_s_barrier();                                         \
    asm volatile("" ::: "memory");                                        \
} while (0)

// ---------------------------------------------------------------------------
// fp32 -> bf16 conversion (all inputs).
// ---------------------------------------------------------------------------
__global__ __launch_bounds__(256)
void cvt_all(const float* __restrict__ q, const float* __restrict__ k,
             const float* __restrict__ v, const float* __restrict__ wq,
             const float* __restrict__ wk, const float* __restrict__ wv,
             const float* __restrict__ wo, ushort* __restrict__ dst)
{
    const int bid = blockIdx.x;
    const float* src;
    size_t dof;
    int local;
    if (bid < 6144) {
        const int t = bid >> 11;
        src = (t == 0) ? q : (t == 1) ? k : v;
        dof = (size_t)t * 4194304u;
        local = bid & 2047;
    } else {
        const int r = bid - 6144;
        const int t = r >> 9;
        src = (t == 0) ? wq : (t == 1) ? wk : (t == 2) ? wv : wo;
        dof = 12582912u + (size_t)t * 1048576u;
        local = r & 511;
    }
    const size_t idx = (size_t)local * 2048 + threadIdx.x * 8;
    const float4 a = *(const float4*)(src + idx);
    const float4 b = *(const float4*)(src + idx + 4);
    u16x8 o;
    o[0] = f2bf(a.x); o[1] = f2bf(a.y); o[2] = f2bf(a.z); o[3] = f2bf(a.w);
    o[4] = f2bf(b.x); o[5] = f2bf(b.y); o[6] = f2bf(b.z); o[7] = f2bf(b.w);
    *(u16x8*)(dst + dof + idx) = o;
}

// ---------------------------------------------------------------------------
// 256x256xBK64 pipelined GEMM core for the QKV projections (R3, kept).
// ---------------------------------------------------------------------------
template<int SWAP>
__device__ __forceinline__ void qkv_core(const ushort* __restrict__ X,
                                         const ushort* __restrict__ W,
                                         int m0, int n0,
                                         f32x4 acc[8][4], ushort* sh)
{
    const int tid  = threadIdx.x;
    const int lane = tid & 63;
    const int w    = tid >> 6;          // 0..7
    const int wm   = w & 1;             // 2 M-waves
    const int wn   = w >> 1;            // 4 N-waves
    const int l15  = lane & 15, quad = lane >> 4;

    const int srow = lane >> 3, schunk = lane & 7;
    const int scol = (schunk ^ srow) * 8;          // row&7 == srow
    const ushort* pa[4]; const ushort* pb[4]; int loff[4];
    #pragma unroll
    for (int i = 0; i < 4; ++i) {
        const int row = (w * 4 + i) * 8 + srow;
        pa[i] = X + (size_t)(m0 + row) * K_ + scol;
        pb[i] = W + (size_t)(n0 + row) * K_ + scol;
        loff[i] = (w * 4 + i) * 512 + lane * 8;
    }

    const f32x4 zero = {0.f, 0.f, 0.f, 0.f};
    #pragma unroll
    for (int mt = 0; mt < 8; ++mt)
        #pragma unroll
        for (int nt = 0; nt < 4; ++nt) acc[mt][nt] = zero;

    #pragma unroll
    for (int i = 0; i < 4; ++i) {
        gl_lds16(pa[i],      sh + loff[i]);
        gl_lds16(pb[i],      sh + 16384 + loff[i]);
    }
    #pragma unroll
    for (int i = 0; i < 4; ++i) {
        gl_lds16(pa[i] + 64, sh + 32768 + loff[i]);
        gl_lds16(pb[i] + 64, sh + 32768 + 16384 + loff[i]);
    }

    const int arow = wm * 128 + l15;               // + mt*16
    const int brow = wn * 64 + l15;                // + nt*16

    for (int t = 0; t < 16; ++t) {
        ushort* curA = sh + (t & 1) * 32768;
        ushort* curB = curA + 16384;

        if (t < 15) { FL_SYNC(8); } else { FL_SYNC(0); }

        __builtin_amdgcn_s_setprio(1);
        #pragma unroll
        for (int kc = 0; kc < 2; ++kc) {
            short8 bf[4];
            #pragma unroll
            for (int nt = 0; nt < 4; ++nt) {
                const int r = brow + nt * 16;
                bf[nt] = *(const short8*)(curB + r * 64 + (((kc * 4 + quad) ^ (r & 7)) * 8));
            }
            #pragma unroll
            for (int mt = 0; mt < 8; ++mt) {
                const int r = arow + mt * 16;
                const short8 af = *(const short8*)(curA + r * 64 + (((kc * 4 + quad) ^ (r & 7)) * 8));
                #pragma unroll
                for (int nt = 0; nt < 4; ++nt) {
                    if (SWAP)
                        acc[mt][nt] = __builtin_amdgcn_mfma_f32_16x16x32_bf16(bf[nt], af, acc[mt][nt], 0, 0, 0);
                    else
                        acc[mt][nt] = __builtin_amdgcn_mfma_f32_16x16x32_bf16(af, bf[nt], acc[mt][nt], 0, 0, 0);
                }
            }
        }
        __builtin_amdgcn_s_setprio(0);

        if (t + 2 < 16) {
            WAITL0_BAR();                       // all waves done reading buf(t&1)
            const int k0 = (t + 2) * 64;
            #pragma unroll
            for (int i = 0; i < 4; ++i) {
                gl_lds16(pa[i] + k0, curA + loff[i]);
                gl_lds16(pb[i] + k0, curB + loff[i]);
            }
        }
    }
}

// QKV projections. z=0: Q -> [B,H,S,D] scaled by QSCALE (swapped, d-contig
// u16x4 stores). z=1: K -> [B,H,S,D] (swapped). z=2: V -> [B,H,D,S].
__global__ __launch_bounds__(512, 2)
void gemm_qkv(const ushort* __restrict__ Xq, const ushort* __restrict__ Xk,
              const ushort* __restrict__ Xv, const ushort* __restrict__ Wq,
              const ushort* __restrict__ Wk, const ushort* __restrict__ Wv,
              const float* __restrict__ bq, const float* __restrict__ bk,
              const float* __restrict__ bv, ushort* __restrict__ Qh,
              ushort* __restrict__ Kh, ushort* __restrict__ Vt)
{
    __shared__ ushort sh[65536];                   // 128 KB
    const int z = blockIdx.z;
    const ushort* X = (z == 0) ? Xq : (z == 1) ? Xk : Xv;
    const ushort* W = (z == 0) ? Wq : (z == 1) ? Wk : Wv;
    const float* bias = (z == 0) ? bq : (z == 1) ? bk : bv;
    ushort* dst = (z == 0) ? Qh : (z == 1) ? Kh : Vt;

    const int m0 = blockIdx.y * 256, n0 = blockIdx.x * 256;
    f32x4 acc[8][4];
    const int lane = threadIdx.x & 63, w = threadIdx.x >> 6;
    const int wm = w & 1, wn = w >> 1;
    const int l15 = lane & 15, quad = lane >> 4;

    if (z < 2) {
        qkv_core<1>(X, W, m0, n0, acc, sh);
        const float qsc = (z == 0) ? QSCALE : 1.0f;
        #pragma unroll
        for (int nt = 0; nt < 4; ++nt) {
            const int nb = n0 + wn * 64 + nt * 16 + quad * 4;   // feature dim
            const int h = nb >> 6, d0 = nb & 63;
            const float4 b4 = *(const float4*)(bias + nb);
            const float bb4[4] = {b4.x, b4.y, b4.z, b4.w};
            #pragma unroll
            for (int mt = 0; mt < 8; ++mt) {
                const int tok = m0 + wm * 128 + mt * 16 + l15;
                const int b = tok >> 11, s = tok & (S_ - 1);
                u16x4 pk;
                #pragma unroll
                for (int r = 0; r < 4; ++r)
                    pk[r] = f2bf((acc[mt][nt][r] + bb4[r]) * qsc);
                *(u16x4*)&dst[(((size_t)(b * H_ + h) * S_) + s) * D_ + d0] = pk;
            }
        }
    } else {
        qkv_core<0>(X, W, m0, n0, acc, sh);
        float bias4[4];
        #pragma unroll
        for (int nt = 0; nt < 4; ++nt)
            bias4[nt] = bias[n0 + wn * 64 + nt * 16 + l15];
        #pragma unroll
        for (int mt = 0; mt < 8; ++mt) {
            const int mrow0 = m0 + wm * 128 + mt * 16 + (quad * 4);
            const int b = mrow0 >> 11;
            const int s0 = mrow0 & (S_ - 1);
            #pragma unroll
            for (int nt = 0; nt < 4; ++nt) {
                const int n = n0 + wn * 64 + nt * 16 + l15;
                const int h = n >> 6, d = n & 63;
                u16x4 pk;
                #pragma unroll
                for (int r = 0; r < 4; ++r) pk[r] = f2bf(acc[mt][nt][r] + bias4[nt]);
                *(u16x4*)&Vt[(((size_t)(b * H_ + h) * D_) + d) * S_ + s0] = pk;
            }
        }
    }
}

// ---------------------------------------------------------------------------
// Final projection: out(fp32) = AO . Wo^T + bo.
// 128x64 tile (512 blocks = 2/CU).
// ---------------------------------------------------------------------------
__global__ __launch_bounds__(256)
void gemm_out(const ushort* __restrict__ X, const ushort* __restrict__ W,
              const float* __restrict__ bias, float* __restrict__ out)
{
    __shared__ ushort Ast[128 * 32];   // 8 KB
    __shared__ ushort Bst[64 * 32];    // 4 KB
    const int m0 = blockIdx.y * 128, n0 = blockIdx.x * 64;
    const int tid = threadIdx.x, lane = tid & 63, w = tid >> 6;
    const int wm = w & 1, wn = w >> 1;
    const int l15 = lane & 15, quad = lane >> 4;
    const int r0 = tid >> 2, c8 = (tid & 3) * 8;
    const int kb = quad * 8;

    const f32x4 zero = {0.f, 0.f, 0.f, 0.f};
    f32x4 acc[4][2];
    #pragma unroll
    for (int mt = 0; mt < 4; ++mt)
        #pragma unroll
        for (int nt = 0; nt < 2; ++nt) acc[mt][nt] = zero;

    for (int k0 = 0; k0 < K_; k0 += 32) {
        __syncthreads();
        const ushort* ga = X + (size_t)(m0 + r0) * K_ + k0 + c8;
        gl_lds16(ga, Ast + tid * 8);
        gl_lds16(ga + (size_t)64 * K_, Ast + 2048 + tid * 8);
        const ushort* gb = W + (size_t)(n0 + r0) * K_ + k0 + c8;
        gl_lds16(gb, Bst + tid * 8);
        __syncthreads();

        short8 af[4], bf[2];
        #pragma unroll
        for (int mt = 0; mt < 4; ++mt)
            af[mt] = *(const short8*)(Ast + (wm * 64 + mt * 16 + l15) * 32 + kb);
        #pragma unroll
        for (int nt = 0; nt < 2; ++nt)
            bf[nt] = *(const short8*)(Bst + (wn * 32 + nt * 16 + l15) * 32 + kb);
        #pragma unroll
        for (int mt = 0; mt < 4; ++mt)
            #pragma unroll
            for (int nt = 0; nt < 2; ++nt)
                acc[mt][nt] = __builtin_amdgcn_mfma_f32_16x16x32_bf16(af[mt], bf[nt], acc[mt][nt], 0, 0, 0);
    }

    float bias2[2];
    #pragma unroll
    for (int nt = 0; nt < 2; ++nt)
        bias2[nt] = bias[n0 + wn * 32 + nt * 16 + l15];

    #pragma unroll
    for (int mt = 0; mt < 4; ++mt) {
        const int mrow0 = m0 + wm * 64 + mt * 16 + quad * 4;
        #pragma unroll
        for (int nt = 0; nt < 2; ++nt) {
            const int n = n0 + wn * 32 + nt * 16 + l15;
            #pragma unroll
            for (int r = 0; r < 4; ++r)
                out[(size_t)(mrow0 + r) * E_ + n] = acc[mt][nt][r] + bias2[nt];
        }
    }
}

// ---------------------------------------------------------------------------
// Flash attention R9: R8's q-split QBLK=128 + cvt_pk, now with a 4-SLOT K/V
// ring (80 KB LDS, still 2 blocks/CU) which makes the per-tile WAITL0_BAR
// unnecessary: stage(j+2) targets slot (j-2)&3, whose reads completed
// before FL_SYNC(j-1) by barrier ordering (R2 harness-validated this
// pattern at distance 1; this is distance 2). Barriers/tile: 2 -> 1, and
// the per-tile lgkmcnt(0) drain disappears. Plus T5: setprio(1) around the
// QK+PV MFMA cluster (catalog: attn +4-7%).
// vmcnt ledger unchanged from R8: prologue Q(4)+s0(4)+s1(4), FL_SYNC(8)
// drains Q; steady FL_SYNC(4) (stage j+1 in flight); tail FL_SYNC(4)/(0).
// Spill guard: WRITE_SIZE == 8192 KB.
// ---------------------------------------------------------------------------
#define NTILE (S_ / 64)
#define QBLK 128

__device__ __forceinline__ void flash_stage(const ushort* __restrict__ Kg,
                                            const ushort* __restrict__ Vg,
                                            size_t qk_off, size_t vt_off,
                                            ushort* sh, int j,
                                            int row0, int gcol0, int row1, int gcol1,
                                            int chunk0, int chunk1, int lane)
{
    ushort* sb = sh + 8192 + (j & 3) * 8192;
    const int j0n = j * 64;
    gl_lds16(Kg + qk_off + (size_t)(j0n + row0) * D_ + gcol0 * 8, sb + chunk0 * 512 + lane * 8);
    gl_lds16(Vg + vt_off + (size_t)row0 * S_ + j0n + gcol0 * 8, sb + 4096 + chunk0 * 512 + lane * 8);
    gl_lds16(Kg + qk_off + (size_t)(j0n + row1) * D_ + gcol1 * 8, sb + chunk1 * 512 + lane * 8);
    gl_lds16(Vg + vt_off + (size_t)row1 * S_ + j0n + gcol1 * 8, sb + 4096 + chunk1 * 512 + lane * 8);
}

__global__ __launch_bounds__(256, 2)
void flash_mfma(const ushort* __restrict__ Qg, const ushort* __restrict__ Kg,
                const ushort* __restrict__ Vg, ushort* __restrict__ AO)
{
    // 80 KB: Qs(8192 u = 128x64) | slot r at 8192 + r*8192: K(4096 u), V(4096 u)
    __shared__ ushort sh[40960];
    ushort* Qs = sh;

    const int tid = threadIdx.x, lane = tid & 63, w = tid >> 6;
    const int l15 = lane & 15, quad = lane >> 4;
    const int q0 = blockIdx.x * QBLK, h = blockIdx.y, b = blockIdx.z;
    const size_t qk_off = (size_t)(b * H_ + h) * S_ * D_;   // [s][d]
    const size_t vt_off = (size_t)(b * H_ + h) * D_ * S_;   // [d][s]

    const int chunk0 = w, chunk1 = w + 4;
    const int row0 = chunk0 * 8 + (lane >> 3);
    const int row1 = chunk1 * 8 + (lane >> 3);
    const int gcol0 = (lane & 7) ^ (row0 & 7);
    const int gcol1 = (lane & 7) ^ (row1 & 7);

    // prologue: Q (4 ops, 128 rows), then K/V tiles 0,1 (4 ops each)
    #pragma unroll
    for (int i = 0; i < 4; ++i) {
        const int qc = w + i * 4;                  // 16 chunks of 8 rows
        const int qrow = qc * 8 + (lane >> 3);
        const int qg = (lane & 7) ^ (qrow & 7);
        gl_lds16(Qg + qk_off + (size_t)(q0 + qrow) * D_ + qg * 8,
                 Qs + qc * 512 + lane * 8);
    }
    flash_stage(Kg, Vg, qk_off, vt_off, sh, 0, row0, gcol0, row1, gcol1, chunk0, chunk1, lane);
    flash_stage(Kg, Vg, qk_off, vt_off, sh, 1, row0, gcol0, row1, gcol1, chunk0, chunk1, lane);

    FL_SYNC(8);                        // Q landed (tiles 0,1 = 8 ops in flight)

    f32x4 o[4][4];                     // o[g][nt]: O[q=qh+g*16+quad*4+r][d=nt*16+l15]
    #pragma unroll
    for (int g = 0; g < 4; ++g)
        #pragma unroll
        for (int nt = 0; nt < 4; ++nt) o[g][nt] = {0.f, 0.f, 0.f, 0.f};
    float lsum[4] = {0.f, 0.f, 0.f, 0.f};  // partial denom, q = qh + g*16 + l15

    const int qh  = (w >> 1) * 64;         // q-half base
    const int kvb = (w & 1) * 32;          // kv-half base within tile
    const int x7  = l15 & 7;
    const int rowA = (kvb + l15) * 64;          // K rows, group A (kv 16-group 0)
    const int rowB = (kvb + 16 + l15) * 64;     // group B
    const int gA = ((w & 1) * 4 + (quad >> 1)) ^ x7;        // V col-group, A
    const int gB = ((w & 1) * 4 + 2 + (quad >> 1)) ^ x7;    // B
    const f32x4 zero = {0.f, 0.f, 0.f, 0.f};

    for (int j = 0; j < NTILE; ++j) {
        const ushort* Kb = sh + 8192 + (j & 3) * 8192;
        const ushort* Vb = Kb + 4096;
        if (j < NTILE - 1) { FL_SYNC(4); } else { FL_SYNC(0); }

        // K frags (both kv-16-groups of this wave's half) + V frags
        const short8 ka0 = *(const short8*)&Kb[rowA + ((quad ^ x7) * 8)];
        const short8 ka1 = *(const short8*)&Kb[rowA + (((4 + quad) ^ x7) * 8)];
        const short8 ka2 = *(const short8*)&Kb[rowB + ((quad ^ x7) * 8)];
        const short8 ka3 = *(const short8*)&Kb[rowB + (((4 + quad) ^ x7) * 8)];
        uint2 vvA[4], vvB[4];
        #pragma unroll
        for (int nt = 0; nt < 4; ++nt) {
            vvA[nt] = *(const uint2*)&Vb[(nt * 16 + l15) * 64 + gA * 8 + (quad & 1) * 4];
            vvB[nt] = *(const uint2*)&Vb[(nt * 16 + l15) * 64 + gB * 8 + (quad & 1) * 4];
        }

        // stage tile j+2 into slot (j+2)&3 = (j-2)&3: idle since tile j-2,
        // all reads of it completed before FL_SYNC(j-1) -> no extra barrier.
        if (j < NTILE - 2)
            flash_stage(Kg, Vg, qk_off, vt_off, sh, j + 2,
                        row0, gcol0, row1, gcol1, chunk0, chunk1, lane);

        __builtin_amdgcn_s_setprio(1);
        // QK both groups + exp2 + cvt_pk pack; Q frags from LDS
        uint2 paLo[4], paHi[4];
        #pragma unroll
        for (int g = 0; g < 4; ++g) {
            const int qr = (qh + g * 16 + l15) * 64;
            const short8 qg0 = *(const short8*)&Qs[qr + ((quad ^ x7) * 8)];
            const short8 qg1 = *(const short8*)&Qs[qr + (((4 + quad) ^ x7) * 8)];
            f32x4 t = __builtin_amdgcn_mfma_f32_16x16x32_bf16(ka0, qg0, zero, 0, 0, 0);
            t = __builtin_amdgcn_mfma_f32_16x16x32_bf16(ka1, qg1, t, 0, 0, 0);
            f32x4 u = __builtin_amdgcn_mfma_f32_16x16x32_bf16(ka2, qg0, zero, 0, 0, 0);
            u = __builtin_amdgcn_mfma_f32_16x16x32_bf16(ka3, qg1, u, 0, 0, 0);
            {
                const float p0 = EXP2F(t[0]), p1 = EXP2F(t[1]);
                const float p2 = EXP2F(t[2]), p3 = EXP2F(t[3]);
                lsum[g] += (p0 + p1) + (p2 + p3);
                paLo[g].x = cvtpk(p0, p1);
                paLo[g].y = cvtpk(p2, p3);
            }
            {
                const float p0 = EXP2F(u[0]), p1 = EXP2F(u[1]);
                const float p2 = EXP2F(u[2]), p3 = EXP2F(u[3]);
                lsum[g] += (p0 + p1) + (p2 + p3);
                paHi[g].x = cvtpk(p0, p1);
                paHi[g].y = cvtpk(p2, p3);
            }
        }

        // PV at full K=32: A-frag = {groupA p (slots 0..3), groupB p (4..7)}
        short8 pa8[4];
        #pragma unroll
        for (int g = 0; g < 4; ++g) {
            u32x4 pk;
            pk[0] = paLo[g].x; pk[1] = paLo[g].y;
            pk[2] = paHi[g].x; pk[3] = paHi[g].y;
            pa8[g] = __builtin_bit_cast(short8, pk);
        }
        #pragma unroll
        for (int nt = 0; nt < 4; ++nt) {
            u32x4 vk;
            vk[0] = vvA[nt].x; vk[1] = vvA[nt].y;
            vk[2] = vvB[nt].x; vk[3] = vvB[nt].y;
            const short8 vb8 = __builtin_bit_cast(short8, vk);
            #pragma unroll
            for (int g = 0; g < 4; ++g)
                o[g][nt] = __builtin_amdgcn_mfma_f32_16x16x32_bf16(pa8[g], vb8, o[g][nt], 0, 0, 0);
        }
        __builtin_amdgcn_s_setprio(0);
    }

    // ---- reduction: intra-wave over quads, then 2-way with partner w^1 ----
    #pragma unroll
    for (int g = 0; g < 4; ++g) {
        lsum[g] += __shfl_xor(lsum[g], 16);
        lsum[g] += __shfl_xor(lsum[g], 32);   // now quad-uniform
    }
    __syncthreads();
    float* fb = (float*)sh;                   // 20480 floats available
    if (w & 1) {                              // waves 1,3 export
        #pragma unroll
        for (int g = 0; g < 4; ++g) {
            #pragma unroll
            for (int nt = 0; nt < 4; ++nt)
                #pragma unroll
                for (int r = 0; r < 4; ++r)
                    fb[(w >> 1) * 4096 + g * 1024 + (nt * 4 + r) * 64 + lane] = o[g][nt][r];
            if (quad == 0) fb[8192 + (w >> 1) * 64 + g * 16 + l15] = lsum[g];
        }
    }
    __syncthreads();
    if (!(w & 1)) {                           // waves 0,2 merge + store
        #pragma unroll
        for (int g = 0; g < 4; ++g) {
            #pragma unroll
            for (int nt = 0; nt < 4; ++nt)
                #pragma unroll
                for (int r = 0; r < 4; ++r)
                    o[g][nt][r] += fb[(w >> 1) * 4096 + g * 1024 + (nt * 4 + r) * 64 + lane];
            lsum[g] += fb[8192 + (w >> 1) * 64 + g * 16 + l15];
        }
        #pragma unroll
        for (int g = 0; g < 4; ++g) {
            const float inv = 1.0f / lsum[g];     // q = qh + g*16 + l15
            float invr[4];
            #pragma unroll
            for (int r = 0; r < 4; ++r)
                invr[r] = __shfl(inv, (lane & 0x30) | (quad * 4 + r));
            #pragma unroll
            for (int nt = 0; nt < 4; ++nt) {
                const int e = h * 64 + nt * 16 + l15;
                #pragma unroll
                for (int r = 0; r < 4; ++r) {
                    const int s = q0 + qh + g * 16 + quad * 4 + r;
                    AO[(size_t)(b * S_ + s) * E_ + e] = f2bf(o[g][nt][r] * invr[r]);
                }
            }
        }
    }
}

// ---------------------------------------------------------------------------
extern "C" void kernel_launch(void* const* d_in, const int* in_sizes, int n_in,
                              void* d_out, int out_size, void* d_ws, size_t ws_size,
                              hipStream_t stream) {
    const float* query = (const float*)d_in[0];
    const float* key   = (const float*)d_in[1];
    const float* value = (const float*)d_in[2];
    const float* Wq = (const float*)d_in[3];
    const float* bq = (const float*)d_in[4];
    const float* Wk = (const float*)d_in[5];
    const float* bk = (const float*)d_in[6];
    const float* Wv = (const float*)d_in[7];
    const float* bv = (const float*)d_in[8];
    const float* Wo = (const float*)d_in[9];
    const float* bo = (const float*)d_in[10];
    float* out = (float*)d_out;

    ushort* ws = (ushort*)d_ws;
    ushort* Xq  = ws;
    ushort* Xk  = ws + 4194304u;
    ushort* Xv  = ws + 8388608u;
    ushort* Wqb = ws + 12582912u;
    ushort* Wkb = ws + 13631488u;
    ushort* Wvb = ws + 14680064u;
    ushort* Wob = ws + 15728640u;
    ushort* Qh  = ws + 16777216u;          // [B,H,S,D] (pre-scaled by QSCALE)
    ushort* Kh  = ws + 20971520u;          // [B,H,S,D]
    ushort* Vt  = ws + 25165824u;          // [B,H,D,S]
    ushort* AO  = ws + 29360128u;          // [B,S,E]

    cvt_all<<<8192, 256, 0, stream>>>(query, key, value, Wq, Wk, Wv, Wo, ws);
    gemm_qkv<<<dim3(4, 16, 3), 512, 0, stream>>>(Xq, Xk, Xv, Wqb, Wkb, Wvb,
                                                 bq, bk, bv, Qh, Kh, Vt);
    flash_mfma<<<dim3(S_ / QBLK, H_, B_), 256, 0, stream>>>(Qh, Kh, Vt, AO);
    gemm_out<<<dim3(16, 32), 256, 0, stream>>>(AO, Wob, bo, out);
}

// Round 10
// 209.978 us; speedup vs baseline: 1.1619x; 1.0271x over previous
//
#include <hip/hip_runtime.h>

#define B_ 2
#define S_ 2048
#define E_ 1024
#define H_ 16
#define D_ 64
#define M_ (B_*S_)
#define K_ E_

typedef __attribute__((ext_vector_type(8))) short  short8;
typedef __attribute__((ext_vector_type(4))) float  f32x4;
typedef __attribute__((ext_vector_type(8))) unsigned short u16x8;
typedef __attribute__((ext_vector_type(4))) unsigned short u16x4;
typedef __attribute__((ext_vector_type(4))) unsigned int   u32x4;

// 0.125 * log2(e): folded into Q so scores arrive in exp2 domain
#define QSCALE 0.18033688011112042f

#if __has_builtin(__builtin_amdgcn_exp2f)
#define EXP2F(x) __builtin_amdgcn_exp2f(x)   // raw v_exp_f32
#else
#define EXP2F(x) exp2f(x)
#endif

__device__ __forceinline__ unsigned short f2bf(float f) {   // RNE
    unsigned u = __float_as_uint(f);
    u += 0x7fffu + ((u >> 16) & 1u);
    return (unsigned short)(u >> 16);
}

// 2x f32 -> packed bf16 in one instruction (lo=a, hi=b), RNE.
// R8 verified: -5.1us on flash, absmax unchanged.
__device__ __forceinline__ unsigned cvtpk(float a, float b) {
    unsigned r;
    asm("v_cvt_pk_bf16_f32 %0, %1, %2" : "=v"(r) : "v"(a), "v"(b));
    return r;
}

__device__ __forceinline__ void gl_lds16(const ushort* g, ushort* l) {
    __builtin_amdgcn_global_load_lds((const __attribute__((address_space(1))) void*)g,
                                     (__attribute__((address_space(3))) void*)l,
                                     16, 0, 0);
}

// counted-vmcnt barrier: wait for all but the newest N vmem ops, then raw
// s_barrier (no compiler vmcnt(0) drain -- the whole point).
#define FL_SYNC(N) do {                                                   \
    asm volatile("s_waitcnt vmcnt(" #N ")" ::: "memory");                 \
    __builtin_amdgcn_s_barrier();                                         \
    asm volatile("" ::: "memory");                                        \
} while (0)

#define WAITL0_BAR() do {                                                 \
    asm volatile("s_waitcnt lgkmcnt(0)" ::: "memory");                    \
    __builtin_amdgcn_s_barrier();                                         \
    asm volatile("" ::: "memory");                                        \
} while (0)

// ---------------------------------------------------------------------------
// fp32 -> bf16 conversion (all inputs).
// ---------------------------------------------------------------------------
__global__ __launch_bounds__(256)
void cvt_all(const float* __restrict__ q, const float* __restrict__ k,
             const float* __restrict__ v, const float* __restrict__ wq,
             const float* __restrict__ wk, const float* __restrict__ wv,
             const float* __restrict__ wo, ushort* __restrict__ dst)
{
    const int bid = blockIdx.x;
    const float* src;
    size_t dof;
    int local;
    if (bid < 6144) {
        const int t = bid >> 11;
        src = (t == 0) ? q : (t == 1) ? k : v;
        dof = (size_t)t * 4194304u;
        local = bid & 2047;
    } else {
        const int r = bid - 6144;
        const int t = r >> 9;
        src = (t == 0) ? wq : (t == 1) ? wk : (t == 2) ? wv : wo;
        dof = 12582912u + (size_t)t * 1048576u;
        local = r & 511;
    }
    const size_t idx = (size_t)local * 2048 + threadIdx.x * 8;
    const float4 a = *(const float4*)(src + idx);
    const float4 b = *(const float4*)(src + idx + 4);
    u16x8 o;
    o[0] = f2bf(a.x); o[1] = f2bf(a.y); o[2] = f2bf(a.z); o[3] = f2bf(a.w);
    o[4] = f2bf(b.x); o[5] = f2bf(b.y); o[6] = f2bf(b.z); o[7] = f2bf(b.w);
    *(u16x8*)(dst + dof + idx) = o;
}

// ---------------------------------------------------------------------------
// 256x256xBK64 pipelined GEMM core for the QKV projections (R3, kept).
// ---------------------------------------------------------------------------
template<int SWAP>
__device__ __forceinline__ void qkv_core(const ushort* __restrict__ X,
                                         const ushort* __restrict__ W,
                                         int m0, int n0,
                                         f32x4 acc[8][4], ushort* sh)
{
    const int tid  = threadIdx.x;
    const int lane = tid & 63;
    const int w    = tid >> 6;          // 0..7
    const int wm   = w & 1;             // 2 M-waves
    const int wn   = w >> 1;            // 4 N-waves
    const int l15  = lane & 15, quad = lane >> 4;

    const int srow = lane >> 3, schunk = lane & 7;
    const int scol = (schunk ^ srow) * 8;          // row&7 == srow
    const ushort* pa[4]; const ushort* pb[4]; int loff[4];
    #pragma unroll
    for (int i = 0; i < 4; ++i) {
        const int row = (w * 4 + i) * 8 + srow;
        pa[i] = X + (size_t)(m0 + row) * K_ + scol;
        pb[i] = W + (size_t)(n0 + row) * K_ + scol;
        loff[i] = (w * 4 + i) * 512 + lane * 8;
    }

    const f32x4 zero = {0.f, 0.f, 0.f, 0.f};
    #pragma unroll
    for (int mt = 0; mt < 8; ++mt)
        #pragma unroll
        for (int nt = 0; nt < 4; ++nt) acc[mt][nt] = zero;

    #pragma unroll
    for (int i = 0; i < 4; ++i) {
        gl_lds16(pa[i],      sh + loff[i]);
        gl_lds16(pb[i],      sh + 16384 + loff[i]);
    }
    #pragma unroll
    for (int i = 0; i < 4; ++i) {
        gl_lds16(pa[i] + 64, sh + 32768 + loff[i]);
        gl_lds16(pb[i] + 64, sh + 32768 + 16384 + loff[i]);
    }

    const int arow = wm * 128 + l15;               // + mt*16
    const int brow = wn * 64 + l15;                // + nt*16

    for (int t = 0; t < 16; ++t) {
        ushort* curA = sh + (t & 1) * 32768;
        ushort* curB = curA + 16384;

        if (t < 15) { FL_SYNC(8); } else { FL_SYNC(0); }

        __builtin_amdgcn_s_setprio(1);
        #pragma unroll
        for (int kc = 0; kc < 2; ++kc) {
            short8 bf[4];
            #pragma unroll
            for (int nt = 0; nt < 4; ++nt) {
                const int r = brow + nt * 16;
                bf[nt] = *(const short8*)(curB + r * 64 + (((kc * 4 + quad) ^ (r & 7)) * 8));
            }
            #pragma unroll
            for (int mt = 0; mt < 8; ++mt) {
                const int r = arow + mt * 16;
                const short8 af = *(const short8*)(curA + r * 64 + (((kc * 4 + quad) ^ (r & 7)) * 8));
                #pragma unroll
                for (int nt = 0; nt < 4; ++nt) {
                    if (SWAP)
                        acc[mt][nt] = __builtin_amdgcn_mfma_f32_16x16x32_bf16(bf[nt], af, acc[mt][nt], 0, 0, 0);
                    else
                        acc[mt][nt] = __builtin_amdgcn_mfma_f32_16x16x32_bf16(af, bf[nt], acc[mt][nt], 0, 0, 0);
                }
            }
        }
        __builtin_amdgcn_s_setprio(0);

        if (t + 2 < 16) {
            WAITL0_BAR();                       // all waves done reading buf(t&1)
            const int k0 = (t + 2) * 64;
            #pragma unroll
            for (int i = 0; i < 4; ++i) {
                gl_lds16(pa[i] + k0, curA + loff[i]);
                gl_lds16(pb[i] + k0, curB + loff[i]);
            }
        }
    }
}

// QKV projections. z=0: Q -> [B,H,S,D] scaled by QSCALE (swapped, d-contig
// u16x4 stores). z=1: K -> [B,H,S,D] (swapped). z=2: V -> [B,H,D,S].
__global__ __launch_bounds__(512, 2)
void gemm_qkv(const ushort* __restrict__ Xq, const ushort* __restrict__ Xk,
              const ushort* __restrict__ Xv, const ushort* __restrict__ Wq,
              const ushort* __restrict__ Wk, const ushort* __restrict__ Wv,
              const float* __restrict__ bq, const float* __restrict__ bk,
              const float* __restrict__ bv, ushort* __restrict__ Qh,
              ushort* __restrict__ Kh, ushort* __restrict__ Vt)
{
    __shared__ ushort sh[65536];                   // 128 KB
    const int z = blockIdx.z;
    const ushort* X = (z == 0) ? Xq : (z == 1) ? Xk : Xv;
    const ushort* W = (z == 0) ? Wq : (z == 1) ? Wk : Wv;
    const float* bias = (z == 0) ? bq : (z == 1) ? bk : bv;
    ushort* dst = (z == 0) ? Qh : (z == 1) ? Kh : Vt;

    const int m0 = blockIdx.y * 256, n0 = blockIdx.x * 256;
    f32x4 acc[8][4];
    const int lane = threadIdx.x & 63, w = threadIdx.x >> 6;
    const int wm = w & 1, wn = w >> 1;
    const int l15 = lane & 15, quad = lane >> 4;

    if (z < 2) {
        qkv_core<1>(X, W, m0, n0, acc, sh);
        const float qsc = (z == 0) ? QSCALE : 1.0f;
        #pragma unroll
        for (int nt = 0; nt < 4; ++nt) {
            const int nb = n0 + wn * 64 + nt * 16 + quad * 4;   // feature dim
            const int h = nb >> 6, d0 = nb & 63;
            const float4 b4 = *(const float4*)(bias + nb);
            const float bb4[4] = {b4.x, b4.y, b4.z, b4.w};
            #pragma unroll
            for (int mt = 0; mt < 8; ++mt) {
                const int tok = m0 + wm * 128 + mt * 16 + l15;
                const int b = tok >> 11, s = tok & (S_ - 1);
                u16x4 pk;
                #pragma unroll
                for (int r = 0; r < 4; ++r)
                    pk[r] = f2bf((acc[mt][nt][r] + bb4[r]) * qsc);
                *(u16x4*)&dst[(((size_t)(b * H_ + h) * S_) + s) * D_ + d0] = pk;
            }
        }
    } else {
        qkv_core<0>(X, W, m0, n0, acc, sh);
        float bias4[4];
        #pragma unroll
        for (int nt = 0; nt < 4; ++nt)
            bias4[nt] = bias[n0 + wn * 64 + nt * 16 + l15];
        #pragma unroll
        for (int mt = 0; mt < 8; ++mt) {
            const int mrow0 = m0 + wm * 128 + mt * 16 + (quad * 4);
            const int b = mrow0 >> 11;
            const int s0 = mrow0 & (S_ - 1);
            #pragma unroll
            for (int nt = 0; nt < 4; ++nt) {
                const int n = n0 + wn * 64 + nt * 16 + l15;
                const int h = n >> 6, d = n & 63;
                u16x4 pk;
                #pragma unroll
                for (int r = 0; r < 4; ++r) pk[r] = f2bf(acc[mt][nt][r] + bias4[nt]);
                *(u16x4*)&Vt[(((size_t)(b * H_ + h) * D_) + d) * S_ + s0] = pk;
            }
        }
    }
}

// ---------------------------------------------------------------------------
// Final projection R10: out(fp32) = AO . Wo^T + bo. 128x64 tile, 512 blocks
// (2/CU balanced), now on the R9-validated 4-slot counted-vmcnt ring:
// slot s = 12 KB {A 128x32 | B 64x32}, 48 KB total; stage(t+2) targets slot
// (t-2)&3 whose reads completed before FL_SYNC(t-1) (barrier-ordering, same
// proof as flash R9) -> ZERO per-step lgkmcnt drains, 1 barrier/step vs 2
// full-drain barriers in the old m97-style loop. 3 staging ops/thread/step:
// ledger = prologue 6 -> FL_SYNC(3) lands tile 0; steady FL_SYNC(3)
// (tile t+1's 3 ops in flight); tail FL_SYNC(0). setprio around MFMA (T5).
// ---------------------------------------------------------------------------
__global__ __launch_bounds__(256)
void gemm_out(const ushort* __restrict__ X, const ushort* __restrict__ W,
              const float* __restrict__ bias, float* __restrict__ out)
{
    __shared__ ushort sh[24576];       // 48 KB: 4 slots x 6144 ushorts
    const int m0 = blockIdx.y * 128, n0 = blockIdx.x * 64;
    const int tid = threadIdx.x, lane = tid & 63, w = tid >> 6;
    const int wm = w & 1, wn = w >> 1;
    const int l15 = lane & 15, quad = lane >> 4;
    const int r0 = tid >> 2, c8 = (tid & 3) * 8;
    const int kb = quad * 8;

    const ushort* ga = X + (size_t)(m0 + r0) * K_ + c8;
    const ushort* gb = W + (size_t)(n0 + r0) * K_ + c8;

    const f32x4 zero = {0.f, 0.f, 0.f, 0.f};
    f32x4 acc[4][2];
    #pragma unroll
    for (int mt = 0; mt < 4; ++mt)
        #pragma unroll
        for (int nt = 0; nt < 2; ++nt) acc[mt][nt] = zero;

    // prologue: stage K-steps 0 and 1 (3 ops/thread each)
    #pragma unroll
    for (int t0 = 0; t0 < 2; ++t0) {
        ushort* sb = sh + t0 * 6144;
        gl_lds16(ga + t0 * 32,                 sb + tid * 8);
        gl_lds16(ga + t0 * 32 + (size_t)64 * K_, sb + 2048 + tid * 8);
        gl_lds16(gb + t0 * 32,                 sb + 4096 + tid * 8);
    }

    for (int t = 0; t < 32; ++t) {
        ushort* sb = sh + (t & 3) * 6144;

        if (t < 31) { FL_SYNC(3); } else { FL_SYNC(0); }

        short8 af[4], bf[2];
        #pragma unroll
        for (int mt = 0; mt < 4; ++mt)
            af[mt] = *(const short8*)(sb + (wm * 64 + mt * 16 + l15) * 32 + kb);
        #pragma unroll
        for (int nt = 0; nt < 2; ++nt)
            bf[nt] = *(const short8*)(sb + 4096 + (wn * 32 + nt * 16 + l15) * 32 + kb);

        // stage K-step t+2 into slot (t+2)&3 = (t-2)&3 (idle; reads done
        // before FL_SYNC(t-1) by barrier ordering -- R9 proof).
        if (t + 2 < 32) {
            ushort* nb = sh + ((t + 2) & 3) * 6144;
            const int k0 = (t + 2) * 32;
            gl_lds16(ga + k0,                 nb + tid * 8);
            gl_lds16(ga + k0 + (size_t)64 * K_, nb + 2048 + tid * 8);
            gl_lds16(gb + k0,                 nb + 4096 + tid * 8);
        }

        __builtin_amdgcn_s_setprio(1);
        #pragma unroll
        for (int mt = 0; mt < 4; ++mt)
            #pragma unroll
            for (int nt = 0; nt < 2; ++nt)
                acc[mt][nt] = __builtin_amdgcn_mfma_f32_16x16x32_bf16(af[mt], bf[nt], acc[mt][nt], 0, 0, 0);
        __builtin_amdgcn_s_setprio(0);
    }

    float bias2[2];
    #pragma unroll
    for (int nt = 0; nt < 2; ++nt)
        bias2[nt] = bias[n0 + wn * 32 + nt * 16 + l15];

    #pragma unroll
    for (int mt = 0; mt < 4; ++mt) {
        const int mrow0 = m0 + wm * 64 + mt * 16 + quad * 4;
        #pragma unroll
        for (int nt = 0; nt < 2; ++nt) {
            const int n = n0 + wn * 32 + nt * 16 + l15;
            #pragma unroll
            for (int r = 0; r < 4; ++r)
                out[(size_t)(mrow0 + r) * E_ + n] = acc[mt][nt][r] + bias2[nt];
        }
    }
}

// ---------------------------------------------------------------------------
// Flash attention R9 (kept): q-split QBLK=128, 4-slot ring, counted vmcnt,
// cvt_pk, setprio. 47 us measured, matched prediction.
// Spill guard: WRITE_SIZE == 8192 KB.
// ---------------------------------------------------------------------------
#define NTILE (S_ / 64)
#define QBLK 128

__device__ __forceinline__ void flash_stage(const ushort* __restrict__ Kg,
                                            const ushort* __restrict__ Vg,
                                            size_t qk_off, size_t vt_off,
                                            ushort* sh, int j,
                                            int row0, int gcol0, int row1, int gcol1,
                                            int chunk0, int chunk1, int lane)
{
    ushort* sb = sh + 8192 + (j & 3) * 8192;
    const int j0n = j * 64;
    gl_lds16(Kg + qk_off + (size_t)(j0n + row0) * D_ + gcol0 * 8, sb + chunk0 * 512 + lane * 8);
    gl_lds16(Vg + vt_off + (size_t)row0 * S_ + j0n + gcol0 * 8, sb + 4096 + chunk0 * 512 + lane * 8);
    gl_lds16(Kg + qk_off + (size_t)(j0n + row1) * D_ + gcol1 * 8, sb + chunk1 * 512 + lane * 8);
    gl_lds16(Vg + vt_off + (size_t)row1 * S_ + j0n + gcol1 * 8, sb + 4096 + chunk1 * 512 + lane * 8);
}

__global__ __launch_bounds__(256, 2)
void flash_mfma(const ushort* __restrict__ Qg, const ushort* __restrict__ Kg,
                const ushort* __restrict__ Vg, ushort* __restrict__ AO)
{
    // 80 KB: Qs(8192 u = 128x64) | slot r at 8192 + r*8192: K(4096 u), V(4096 u)
    __shared__ ushort sh[40960];
    ushort* Qs = sh;

    const int tid = threadIdx.x, lane = tid & 63, w = tid >> 6;
    const int l15 = lane & 15, quad = lane >> 4;
    const int q0 = blockIdx.x * QBLK, h = blockIdx.y, b = blockIdx.z;
    const size_t qk_off = (size_t)(b * H_ + h) * S_ * D_;   // [s][d]
    const size_t vt_off = (size_t)(b * H_ + h) * D_ * S_;   // [d][s]

    const int chunk0 = w, chunk1 = w + 4;
    const int row0 = chunk0 * 8 + (lane >> 3);
    const int row1 = chunk1 * 8 + (lane >> 3);
    const int gcol0 = (lane & 7) ^ (row0 & 7);
    const int gcol1 = (lane & 7) ^ (row1 & 7);

    // prologue: Q (4 ops, 128 rows), then K/V tiles 0,1 (4 ops each)
    #pragma unroll
    for (int i = 0; i < 4; ++i) {
        const int qc = w + i * 4;                  // 16 chunks of 8 rows
        const int qrow = qc * 8 + (lane >> 3);
        const int qg = (lane & 7) ^ (qrow & 7);
        gl_lds16(Qg + qk_off + (size_t)(q0 + qrow) * D_ + qg * 8,
                 Qs + qc * 512 + lane * 8);
    }
    flash_stage(Kg, Vg, qk_off, vt_off, sh, 0, row0, gcol0, row1, gcol1, chunk0, chunk1, lane);
    flash_stage(Kg, Vg, qk_off, vt_off, sh, 1, row0, gcol0, row1, gcol1, chunk0, chunk1, lane);

    FL_SYNC(8);                        // Q landed (tiles 0,1 = 8 ops in flight)

    f32x4 o[4][4];                     // o[g][nt]: O[q=qh+g*16+quad*4+r][d=nt*16+l15]
    #pragma unroll
    for (int g = 0; g < 4; ++g)
        #pragma unroll
        for (int nt = 0; nt < 4; ++nt) o[g][nt] = {0.f, 0.f, 0.f, 0.f};
    float lsum[4] = {0.f, 0.f, 0.f, 0.f};  // partial denom, q = qh + g*16 + l15

    const int qh  = (w >> 1) * 64;         // q-half base
    const int kvb = (w & 1) * 32;          // kv-half base within tile
    const int x7  = l15 & 7;
    const int rowA = (kvb + l15) * 64;          // K rows, group A (kv 16-group 0)
    const int rowB = (kvb + 16 + l15) * 64;     // group B
    const int gA = ((w & 1) * 4 + (quad >> 1)) ^ x7;        // V col-group, A
    const int gB = ((w & 1) * 4 + 2 + (quad >> 1)) ^ x7;    // B
    const f32x4 zero = {0.f, 0.f, 0.f, 0.f};

    for (int j = 0; j < NTILE; ++j) {
        const ushort* Kb = sh + 8192 + (j & 3) * 8192;
        const ushort* Vb = Kb + 4096;
        if (j < NTILE - 1) { FL_SYNC(4); } else { FL_SYNC(0); }

        // K frags (both kv-16-groups of this wave's half) + V frags
        const short8 ka0 = *(const short8*)&Kb[rowA + ((quad ^ x7) * 8)];
        const short8 ka1 = *(const short8*)&Kb[rowA + (((4 + quad) ^ x7) * 8)];
        const short8 ka2 = *(const short8*)&Kb[rowB + ((quad ^ x7) * 8)];
        const short8 ka3 = *(const short8*)&Kb[rowB + (((4 + quad) ^ x7) * 8)];
        uint2 vvA[4], vvB[4];
        #pragma unroll
        for (int nt = 0; nt < 4; ++nt) {
            vvA[nt] = *(const uint2*)&Vb[(nt * 16 + l15) * 64 + gA * 8 + (quad & 1) * 4];
            vvB[nt] = *(const uint2*)&Vb[(nt * 16 + l15) * 64 + gB * 8 + (quad & 1) * 4];
        }

        // stage tile j+2 into slot (j+2)&3 = (j-2)&3: idle since tile j-2,
        // all reads of it completed before FL_SYNC(j-1) -> no extra barrier.
        if (j < NTILE - 2)
            flash_stage(Kg, Vg, qk_off, vt_off, sh, j + 2,
                        row0, gcol0, row1, gcol1, chunk0, chunk1, lane);

        __builtin_amdgcn_s_setprio(1);
        // QK both groups + exp2 + cvt_pk pack; Q frags from LDS
        uint2 paLo[4], paHi[4];
        #pragma unroll
        for (int g = 0; g < 4; ++g) {
            const int qr = (qh + g * 16 + l15) * 64;
            const short8 qg0 = *(const short8*)&Qs[qr + ((quad ^ x7) * 8)];
            const short8 qg1 = *(const short8*)&Qs[qr + (((4 + quad) ^ x7) * 8)];
            f32x4 t = __builtin_amdgcn_mfma_f32_16x16x32_bf16(ka0, qg0, zero, 0, 0, 0);
            t = __builtin_amdgcn_mfma_f32_16x16x32_bf16(ka1, qg1, t, 0, 0, 0);
            f32x4 u = __builtin_amdgcn_mfma_f32_16x16x32_bf16(ka2, qg0, zero, 0, 0, 0);
            u = __builtin_amdgcn_mfma_f32_16x16x32_bf16(ka3, qg1, u, 0, 0, 0);
            {
                const float p0 = EXP2F(t[0]), p1 = EXP2F(t[1]);
                const float p2 = EXP2F(t[2]), p3 = EXP2F(t[3]);
                lsum[g] += (p0 + p1) + (p2 + p3);
                paLo[g].x = cvtpk(p0, p1);
                paLo[g].y = cvtpk(p2, p3);
            }
            {
                const float p0 = EXP2F(u[0]), p1 = EXP2F(u[1]);
                const float p2 = EXP2F(u[2]), p3 = EXP2F(u[3]);
                lsum[g] += (p0 + p1) + (p2 + p3);
                paHi[g].x = cvtpk(p0, p1);
                paHi[g].y = cvtpk(p2, p3);
            }
        }

        // PV at full K=32: A-frag = {groupA p (slots 0..3), groupB p (4..7)}
        short8 pa8[4];
        #pragma unroll
        for (int g = 0; g < 4; ++g) {
            u32x4 pk;
            pk[0] = paLo[g].x; pk[1] = paLo[g].y;
            pk[2] = paHi[g].x; pk[3] = paHi[g].y;
            pa8[g] = __builtin_bit_cast(short8, pk);
        }
        #pragma unroll
        for (int nt = 0; nt < 4; ++nt) {
            u32x4 vk;
            vk[0] = vvA[nt].x; vk[1] = vvA[nt].y;
            vk[2] = vvB[nt].x; vk[3] = vvB[nt].y;
            const short8 vb8 = __builtin_bit_cast(short8, vk);
            #pragma unroll
            for (int g = 0; g < 4; ++g)
                o[g][nt] = __builtin_amdgcn_mfma_f32_16x16x32_bf16(pa8[g], vb8, o[g][nt], 0, 0, 0);
        }
        __builtin_amdgcn_s_setprio(0);
    }

    // ---- reduction: intra-wave over quads, then 2-way with partner w^1 ----
    #pragma unroll
    for (int g = 0; g < 4; ++g) {
        lsum[g] += __shfl_xor(lsum[g], 16);
        lsum[g] += __shfl_xor(lsum[g], 32);   // now quad-uniform
    }
    __syncthreads();
    float* fb = (float*)sh;                   // 20480 floats available
    if (w & 1) {                              // waves 1,3 export
        #pragma unroll
        for (int g = 0; g < 4; ++g) {
            #pragma unroll
            for (int nt = 0; nt < 4; ++nt)
                #pragma unroll
                for (int r = 0; r < 4; ++r)
                    fb[(w >> 1) * 4096 + g * 1024 + (nt * 4 + r) * 64 + lane] = o[g][nt][r];
            if (quad == 0) fb[8192 + (w >> 1) * 64 + g * 16 + l15] = lsum[g];
        }
    }
    __syncthreads();
    if (!(w & 1)) {                           // waves 0,2 merge + store
        #pragma unroll
        for (int g = 0; g < 4; ++g) {
            #pragma unroll
            for (int nt = 0; nt < 4; ++nt)
                #pragma unroll
                for (int r = 0; r < 4; ++r)
                    o[g][nt][r] += fb[(w >> 1) * 4096 + g * 1024 + (nt * 4 + r) * 64 + lane];
            lsum[g] += fb[8192 + (w >> 1) * 64 + g * 16 + l15];
        }
        #pragma unroll
        for (int g = 0; g < 4; ++g) {
            const float inv = 1.0f / lsum[g];     // q = qh + g*16 + l15
            float invr[4];
            #pragma unroll
            for (int r = 0; r < 4; ++r)
                invr[r] = __shfl(inv, (lane & 0x30) | (quad * 4 + r));
            #pragma unroll
            for (int nt = 0; nt < 4; ++nt) {
                const int e = h * 64 + nt * 16 + l15;
                #pragma unroll
                for (int r = 0; r < 4; ++r) {
                    const int s = q0 + qh + g * 16 + quad * 4 + r;
                    AO[(size_t)(b * S_ + s) * E_ + e] = f2bf(o[g][nt][r] * invr[r]);
                }
            }
        }
    }
}

// ---------------------------------------------------------------------------
extern "C" void kernel_launch(void* const* d_in, const int* in_sizes, int n_in,
                              void* d_out, int out_size, void* d_ws, size_t ws_size,
                              hipStream_t stream) {
    const float* query = (const float*)d_in[0];
    const float* key   = (const float*)d_in[1];
    const float* value = (const float*)d_in[2];
    const float* Wq = (const float*)d_in[3];
    const float* bq = (const float*)d_in[4];
    const float* Wk = (const float*)d_in[5];
    const float* bk = (const float*)d_in[6];
    const float* Wv = (const float*)d_in[7];
    const float* bv = (const float*)d_in[8];
    const float* Wo = (const float*)d_in[9];
    const float* bo = (const float*)d_in[10];
    float* out = (float*)d_out;

    ushort* ws = (ushort*)d_ws;
    ushort* Xq  = ws;
    ushort* Xk  = ws + 4194304u;
    ushort* Xv  = ws + 8388608u;
    ushort* Wqb = ws + 12582912u;
    ushort* Wkb = ws + 13631488u;
    ushort* Wvb = ws + 14680064u;
    ushort* Wob = ws + 15728640u;
    ushort* Qh  = ws + 16777216u;          // [B,H,S,D] (pre-scaled by QSCALE)
    ushort* Kh  = ws + 20971520u;          // [B,H,S,D]
    ushort* Vt  = ws + 25165824u;          // [B,H,D,S]
    ushort* AO  = ws + 29360128u;          // [B,S,E]

    cvt_all<<<8192, 256, 0, stream>>>(query, key, value, Wq, Wk, Wv, Wo, ws);
    gemm_qkv<<<dim3(4, 16, 3), 512, 0, stream>>>(Xq, Xk, Xv, Wqb, Wkb, Wvb,
                                                 bq, bk, bv, Qh, Kh, Vt);
    flash_mfma<<<dim3(S_ / QBLK, H_, B_), 256, 0, stream>>>(Qh, Kh, Vt, AO);
    gemm_out<<<dim3(16, 32), 256, 0, stream>>>(AO, Wob, bo, out);
}

// Round 12
// 208.034 us; speedup vs baseline: 1.1728x; 1.0093x over previous
//
#include <hip/hip_runtime.h>

#define B_ 2
#define S_ 2048
#define E_ 1024
#define H_ 16
#define D_ 64
#define M_ (B_*S_)
#define K_ E_

typedef __attribute__((ext_vector_type(8))) short  short8;
typedef __attribute__((ext_vector_type(4))) float  f32x4;
typedef __attribute__((ext_vector_type(8))) unsigned short u16x8;
typedef __attribute__((ext_vector_type(4))) unsigned short u16x4;
typedef __attribute__((ext_vector_type(4))) unsigned int   u32x4;

// 0.125 * log2(e): folded into Q so scores arrive in exp2 domain
#define QSCALE 0.18033688011112042f

#if __has_builtin(__builtin_amdgcn_exp2f)
#define EXP2F(x) __builtin_amdgcn_exp2f(x)   // raw v_exp_f32
#else
#define EXP2F(x) exp2f(x)
#endif

__device__ __forceinline__ unsigned short f2bf(float f) {   // RNE
    unsigned u = __float_as_uint(f);
    u += 0x7fffu + ((u >> 16) & 1u);
    return (unsigned short)(u >> 16);
}

// 2x f32 -> packed bf16 in one instruction (lo=a, hi=b), RNE.
__device__ __forceinline__ unsigned cvtpk(float a, float b) {
    unsigned r;
    asm("v_cvt_pk_bf16_f32 %0, %1, %2" : "=v"(r) : "v"(a), "v"(b));
    return r;
}

__device__ __forceinline__ void gl_lds16(const ushort* g, ushort* l) {
    __builtin_amdgcn_global_load_lds((const __attribute__((address_space(1))) void*)g,
                                     (__attribute__((address_space(3))) void*)l,
                                     16, 0, 0);
}

// counted-vmcnt barrier: wait for all but the newest N vmem ops, then raw
// s_barrier. RULE (R9/R10 pass, R11 race): an LDS overwrite is only safe if
// the ds_reads of that region were issued >= 2 barriers earlier (or after an
// explicit lgkmcnt(0) drain). All rings below respect 2-barrier separation.
#define FL_SYNC(N) do {                                                   \
    asm volatile("s_waitcnt vmcnt(" #N ")" ::: "memory");                 \
    __builtin_amdgcn_s_barrier();                                         \
    asm volatile("" ::: "memory");                                        \
} while (0)

#define WAITL0_BAR() do {                                                 \
    asm volatile("s_waitcnt lgkmcnt(0)" ::: "memory");                    \
    __builtin_amdgcn_s_barrier();                                         \
    asm volatile("" ::: "memory");                                        \
} while (0)

// ---------------------------------------------------------------------------
// fp32 -> bf16 conversion (all inputs).
// ---------------------------------------------------------------------------
__global__ __launch_bounds__(256)
void cvt_all(const float* __restrict__ q, const float* __restrict__ k,
             const float* __restrict__ v, const float* __restrict__ wq,
             const float* __restrict__ wk, const float* __restrict__ wv,
             const float* __restrict__ wo, ushort* __restrict__ dst)
{
    const int bid = blockIdx.x;
    const float* src;
    size_t dof;
    int local;
    if (bid < 6144) {
        const int t = bid >> 11;
        src = (t == 0) ? q : (t == 1) ? k : v;
        dof = (size_t)t * 4194304u;
        local = bid & 2047;
    } else {
        const int r = bid - 6144;
        const int t = r >> 9;
        src = (t == 0) ? wq : (t == 1) ? wk : (t == 2) ? wv : wo;
        dof = 12582912u + (size_t)t * 1048576u;
        local = r & 511;
    }
    const size_t idx = (size_t)local * 2048 + threadIdx.x * 8;
    const float4 a = *(const float4*)(src + idx);
    const float4 b = *(const float4*)(src + idx + 4);
    u16x8 o;
    o[0] = f2bf(a.x); o[1] = f2bf(a.y); o[2] = f2bf(a.z); o[3] = f2bf(a.w);
    o[4] = f2bf(b.x); o[5] = f2bf(b.y); o[6] = f2bf(b.z); o[7] = f2bf(b.w);
    *(u16x8*)(dst + dof + idx) = o;
}

// ---------------------------------------------------------------------------
// R12 QKV core: 256x256 tile, BK=32, 4-slot counted-vmcnt ring (the R10
// gemm_out pattern scaled up). Slot = {A 256x32 | B 256x32} = 32 KB; 4 slots
// = 128 KB. stage(t+2) -> slot (t-2)&3, read two barriers ago (safe per the
// 2-barrier rule). Steady FL_SYNC(4); ZERO lgkmcnt(0) drains (R3 had 14).
// XOR swizzle chunk^(row&3) on write (pre-swizzled source col) and read.
// ---------------------------------------------------------------------------
#define QKV_STAGE(t) do {                                                  \
    ushort* sb_ = sh + ((t) & 3) * 16384;                                  \
    const int k0_ = (t) * 32;                                              \
    gl_lds16(pa0 + k0_, sb_ + ld0);                                        \
    gl_lds16(pa1 + k0_, sb_ + 4096 + ld0);                                 \
    gl_lds16(pb0 + k0_, sb_ + 8192 + ld0);                                 \
    gl_lds16(pb1 + k0_, sb_ + 12288 + ld0);                                \
} while (0)

template<int SWAP>
__device__ __forceinline__ void qkv_core(const ushort* __restrict__ X,
                                         const ushort* __restrict__ W,
                                         int m0, int n0,
                                         f32x4 acc[8][4], ushort* sh)
{
    const int tid  = threadIdx.x;
    const int lane = tid & 63;
    const int w    = tid >> 6;          // 0..7
    const int wm   = w & 1;             // 2 M-waves
    const int wn   = w >> 1;            // 4 N-waves
    const int l15  = lane & 15, quad = lane >> 4;

    // staging: thread tid, part i (0/1): row = i*128 + (tid>>2), dest chunk
    // cidx = tid&3 holds global col-chunk (cidx ^ (row&3)). 128%4==0 so
    // row&3 == (tid>>2)&3 for both parts.
    const int srow = tid >> 2, cidx = tid & 3;
    const int scol = (cidx ^ (srow & 3)) * 8;
    const ushort* pa0 = X + (size_t)(m0 + srow) * K_ + scol;
    const ushort* pa1 = X + (size_t)(m0 + 128 + srow) * K_ + scol;
    const ushort* pb0 = W + (size_t)(n0 + srow) * K_ + scol;
    const ushort* pb1 = W + (size_t)(n0 + 128 + srow) * K_ + scol;
    const int ld0 = tid * 8;

    const f32x4 zero = {0.f, 0.f, 0.f, 0.f};
    #pragma unroll
    for (int mt = 0; mt < 8; ++mt)
        #pragma unroll
        for (int nt = 0; nt < 4; ++nt) acc[mt][nt] = zero;

    // prologue: stage K-steps 0, 1 (4 ops/thread each)
    QKV_STAGE(0);
    QKV_STAGE(1);

    // frag read chunk selector: row&3 == l15&3 for all frag rows
    // (wm*128, wn*64, mt*16, nt*16 all ≡ 0 mod 4)
    const int xq = (quad ^ (l15 & 3)) * 8;
    const int arow = wm * 128 + l15;               // + mt*16
    const int brow = wn * 64 + l15;                // + nt*16

    for (int t = 0; t < 32; ++t) {
        ushort* sb = sh + (t & 3) * 16384;

        if (t < 31) { FL_SYNC(4); } else { FL_SYNC(0); }

        short8 bf[4];
        #pragma unroll
        for (int nt = 0; nt < 4; ++nt)
            bf[nt] = *(const short8*)(sb + 8192 + (brow + nt * 16) * 32 + xq);
        short8 af[8];
        #pragma unroll
        for (int mt = 0; mt < 8; ++mt)
            af[mt] = *(const short8*)(sb + (arow + mt * 16) * 32 + xq);

        // stage K-step t+2 into slot (t-2)&3 (read two barriers ago -- safe)
        if (t + 2 < 32) QKV_STAGE(t + 2);

        __builtin_amdgcn_s_setprio(1);
        #pragma unroll
        for (int mt = 0; mt < 8; ++mt)
            #pragma unroll
            for (int nt = 0; nt < 4; ++nt) {
                if (SWAP)
                    acc[mt][nt] = __builtin_amdgcn_mfma_f32_16x16x32_bf16(bf[nt], af[mt], acc[mt][nt], 0, 0, 0);
                else
                    acc[mt][nt] = __builtin_amdgcn_mfma_f32_16x16x32_bf16(af[mt], bf[nt], acc[mt][nt], 0, 0, 0);
            }
        __builtin_amdgcn_s_setprio(0);
    }
}

// QKV projections. z=0: Q -> [B,H,S,D] scaled by QSCALE (swapped, d-contig
// u16x4 stores). z=1: K -> [B,H,S,D] (swapped). z=2: V -> [B,H,D,S].
__global__ __launch_bounds__(512, 2)
void gemm_qkv(const ushort* __restrict__ Xq, const ushort* __restrict__ Xk,
              const ushort* __restrict__ Xv, const ushort* __restrict__ Wq,
              const ushort* __restrict__ Wk, const ushort* __restrict__ Wv,
              const float* __restrict__ bq, const float* __restrict__ bk,
              const float* __restrict__ bv, ushort* __restrict__ Qh,
              ushort* __restrict__ Kh, ushort* __restrict__ Vt)
{
    __shared__ ushort sh[65536];                   // 128 KB: 4 slots x 32 KB
    const int z = blockIdx.z;
    const ushort* X = (z == 0) ? Xq : (z == 1) ? Xk : Xv;
    const ushort* W = (z == 0) ? Wq : (z == 1) ? Wk : Wv;
    const float* bias = (z == 0) ? bq : (z == 1) ? bk : bv;
    ushort* dst = (z == 0) ? Qh : (z == 1) ? Kh : Vt;

    const int m0 = blockIdx.y * 256, n0 = blockIdx.x * 256;
    f32x4 acc[8][4];
    const int lane = threadIdx.x & 63, w = threadIdx.x >> 6;
    const int wm = w & 1, wn = w >> 1;
    const int l15 = lane & 15, quad = lane >> 4;

    if (z < 2) {
        qkv_core<1>(X, W, m0, n0, acc, sh);
        const float qsc = (z == 0) ? QSCALE : 1.0f;
        #pragma unroll
        for (int nt = 0; nt < 4; ++nt) {
            const int nb = n0 + wn * 64 + nt * 16 + quad * 4;   // feature dim
            const int h = nb >> 6, d0 = nb & 63;
            const float4 b4 = *(const float4*)(bias + nb);
            const float bb4[4] = {b4.x, b4.y, b4.z, b4.w};
            #pragma unroll
            for (int mt = 0; mt < 8; ++mt) {
                const int tok = m0 + wm * 128 + mt * 16 + l15;
                const int b = tok >> 11, s = tok & (S_ - 1);
                u16x4 pk;
                #pragma unroll
                for (int r = 0; r < 4; ++r)
                    pk[r] = f2bf((acc[mt][nt][r] + bb4[r]) * qsc);
                *(u16x4*)&dst[(((size_t)(b * H_ + h) * S_) + s) * D_ + d0] = pk;
            }
        }
    } else {
        qkv_core<0>(X, W, m0, n0, acc, sh);
        float bias4[4];
        #pragma unroll
        for (int nt = 0; nt < 4; ++nt)
            bias4[nt] = bias[n0 + wn * 64 + nt * 16 + l15];
        #pragma unroll
        for (int mt = 0; mt < 8; ++mt) {
            const int mrow0 = m0 + wm * 128 + mt * 16 + (quad * 4);
            const int b = mrow0 >> 11;
            const int s0 = mrow0 & (S_ - 1);
            #pragma unroll
            for (int nt = 0; nt < 4; ++nt) {
                const int n = n0 + wn * 64 + nt * 16 + l15;
                const int h = n >> 6, d = n & 63;
                u16x4 pk;
                #pragma unroll
                for (int r = 0; r < 4; ++r) pk[r] = f2bf(acc[mt][nt][r] + bias4[nt]);
                *(u16x4*)&Vt[(((size_t)(b * H_ + h) * D_) + d) * S_ + s0] = pk;
            }
        }
    }
}

// ---------------------------------------------------------------------------
// Final projection R10 (kept): 4-slot counted-vmcnt ring, -5.7us verified.
// ---------------------------------------------------------------------------
__global__ __launch_bounds__(256)
void gemm_out(const ushort* __restrict__ X, const ushort* __restrict__ W,
              const float* __restrict__ bias, float* __restrict__ out)
{
    __shared__ ushort sh[24576];       // 48 KB: 4 slots x 6144 ushorts
    const int m0 = blockIdx.y * 128, n0 = blockIdx.x * 64;
    const int tid = threadIdx.x, lane = tid & 63, w = tid >> 6;
    const int wm = w & 1, wn = w >> 1;
    const int l15 = lane & 15, quad = lane >> 4;
    const int r0 = tid >> 2, c8 = (tid & 3) * 8;
    const int kb = quad * 8;

    const ushort* ga = X + (size_t)(m0 + r0) * K_ + c8;
    const ushort* gb = W + (size_t)(n0 + r0) * K_ + c8;

    const f32x4 zero = {0.f, 0.f, 0.f, 0.f};
    f32x4 acc[4][2];
    #pragma unroll
    for (int mt = 0; mt < 4; ++mt)
        #pragma unroll
        for (int nt = 0; nt < 2; ++nt) acc[mt][nt] = zero;

    // prologue: stage K-steps 0 and 1 (3 ops/thread each)
    #pragma unroll
    for (int t0 = 0; t0 < 2; ++t0) {
        ushort* sb = sh + t0 * 6144;
        gl_lds16(ga + t0 * 32,                 sb + tid * 8);
        gl_lds16(ga + t0 * 32 + (size_t)64 * K_, sb + 2048 + tid * 8);
        gl_lds16(gb + t0 * 32,                 sb + 4096 + tid * 8);
    }

    for (int t = 0; t < 32; ++t) {
        ushort* sb = sh + (t & 3) * 6144;

        if (t < 31) { FL_SYNC(3); } else { FL_SYNC(0); }

        short8 af[4], bf[2];
        #pragma unroll
        for (int mt = 0; mt < 4; ++mt)
            af[mt] = *(const short8*)(sb + (wm * 64 + mt * 16 + l15) * 32 + kb);
        #pragma unroll
        for (int nt = 0; nt < 2; ++nt)
            bf[nt] = *(const short8*)(sb + 4096 + (wn * 32 + nt * 16 + l15) * 32 + kb);

        if (t + 2 < 32) {
            ushort* nb = sh + ((t + 2) & 3) * 6144;
            const int k0 = (t + 2) * 32;
            gl_lds16(ga + k0,                 nb + tid * 8);
            gl_lds16(ga + k0 + (size_t)64 * K_, nb + 2048 + tid * 8);
            gl_lds16(gb + k0,                 nb + 4096 + tid * 8);
        }

        __builtin_amdgcn_s_setprio(1);
        #pragma unroll
        for (int mt = 0; mt < 4; ++mt)
            #pragma unroll
            for (int nt = 0; nt < 2; ++nt)
                acc[mt][nt] = __builtin_amdgcn_mfma_f32_16x16x32_bf16(af[mt], bf[nt], acc[mt][nt], 0, 0, 0);
        __builtin_amdgcn_s_setprio(0);
    }

    float bias2[2];
    #pragma unroll
    for (int nt = 0; nt < 2; ++nt)
        bias2[nt] = bias[n0 + wn * 32 + nt * 16 + l15];

    #pragma unroll
    for (int mt = 0; mt < 4; ++mt) {
        const int mrow0 = m0 + wm * 64 + mt * 16 + quad * 4;
        #pragma unroll
        for (int nt = 0; nt < 2; ++nt) {
            const int n = n0 + wn * 32 + nt * 16 + l15;
            #pragma unroll
            for (int r = 0; r < 4; ++r)
                out[(size_t)(mrow0 + r) * E_ + n] = acc[mt][nt][r] + bias2[nt];
        }
    }
}

// ---------------------------------------------------------------------------
// Flash attention: R9/R10 config RESTORED VERBATIM (46.6us verified).
// q-split QBLK=128, 4-slot ring (2-barrier separation), counted vmcnt,
// cvt_pk, setprio. R11's 3-slot/1-barrier variant raced (absmax 6.9e-3) and
// its 3-blocks/CU goal was moot (grid 512 = 2/CU by block count).
// Spill guard: WRITE_SIZE == 8192 KB.
// ---------------------------------------------------------------------------
#define NTILE (S_ / 64)
#define QBLK 128

__device__ __forceinline__ void flash_stage(const ushort* __restrict__ Kg,
                                            const ushort* __restrict__ Vg,
                                            size_t qk_off, size_t vt_off,
                                            ushort* sh, int j,
                                            int row0, int gcol0, int row1, int gcol1,
                                            int chunk0, int chunk1, int lane)
{
    ushort* sb = sh + 8192 + (j & 3) * 8192;
    const int j0n = j * 64;
    gl_lds16(Kg + qk_off + (size_t)(j0n + row0) * D_ + gcol0 * 8, sb + chunk0 * 512 + lane * 8);
    gl_lds16(Vg + vt_off + (size_t)row0 * S_ + j0n + gcol0 * 8, sb + 4096 + chunk0 * 512 + lane * 8);
    gl_lds16(Kg + qk_off + (size_t)(j0n + row1) * D_ + gcol1 * 8, sb + chunk1 * 512 + lane * 8);
    gl_lds16(Vg + vt_off + (size_t)row1 * S_ + j0n + gcol1 * 8, sb + 4096 + chunk1 * 512 + lane * 8);
}

__global__ __launch_bounds__(256, 2)
void flash_mfma(const ushort* __restrict__ Qg, const ushort* __restrict__ Kg,
                const ushort* __restrict__ Vg, ushort* __restrict__ AO)
{
    // 80 KB: Qs(8192 u = 128x64) | slot r at 8192 + r*8192: K(4096 u), V(4096 u)
    __shared__ ushort sh[40960];
    ushort* Qs = sh;

    const int tid = threadIdx.x, lane = tid & 63, w = tid >> 6;
    const int l15 = lane & 15, quad = lane >> 4;
    const int q0 = blockIdx.x * QBLK, h = blockIdx.y, b = blockIdx.z;
    const size_t qk_off = (size_t)(b * H_ + h) * S_ * D_;   // [s][d]
    const size_t vt_off = (size_t)(b * H_ + h) * D_ * S_;   // [d][s]

    const int chunk0 = w, chunk1 = w + 4;
    const int row0 = chunk0 * 8 + (lane >> 3);
    const int row1 = chunk1 * 8 + (lane >> 3);
    const int gcol0 = (lane & 7) ^ (row0 & 7);
    const int gcol1 = (lane & 7) ^ (row1 & 7);

    // prologue: Q (4 ops, 128 rows), then K/V tiles 0,1 (4 ops each)
    #pragma unroll
    for (int i = 0; i < 4; ++i) {
        const int qc = w + i * 4;                  // 16 chunks of 8 rows
        const int qrow = qc * 8 + (lane >> 3);
        const int qg = (lane & 7) ^ (qrow & 7);
        gl_lds16(Qg + qk_off + (size_t)(q0 + qrow) * D_ + qg * 8,
                 Qs + qc * 512 + lane * 8);
    }
    flash_stage(Kg, Vg, qk_off, vt_off, sh, 0, row0, gcol0, row1, gcol1, chunk0, chunk1, lane);
    flash_stage(Kg, Vg, qk_off, vt_off, sh, 1, row0, gcol0, row1, gcol1, chunk0, chunk1, lane);

    FL_SYNC(8);                        // Q landed (tiles 0,1 = 8 ops in flight)

    f32x4 o[4][4];                     // o[g][nt]: O[q=qh+g*16+quad*4+r][d=nt*16+l15]
    #pragma unroll
    for (int g = 0; g < 4; ++g)
        #pragma unroll
        for (int nt = 0; nt < 4; ++nt) o[g][nt] = {0.f, 0.f, 0.f, 0.f};
    float lsum[4] = {0.f, 0.f, 0.f, 0.f};  // partial denom, q = qh + g*16 + l15

    const int qh  = (w >> 1) * 64;         // q-half base
    const int kvb = (w & 1) * 32;          // kv-half base within tile
    const int x7  = l15 & 7;
    const int rowA = (kvb + l15) * 64;          // K rows, group A (kv 16-group 0)
    const int rowB = (kvb + 16 + l15) * 64;     // group B
    const int gA = ((w & 1) * 4 + (quad >> 1)) ^ x7;        // V col-group, A
    const int gB = ((w & 1) * 4 + 2 + (quad >> 1)) ^ x7;    // B
    const f32x4 zero = {0.f, 0.f, 0.f, 0.f};

    for (int j = 0; j < NTILE; ++j) {
        const ushort* Kb = sh + 8192 + (j & 3) * 8192;
        const ushort* Vb = Kb + 4096;
        if (j < NTILE - 1) { FL_SYNC(4); } else { FL_SYNC(0); }

        // K frags (both kv-16-groups of this wave's half) + V frags
        const short8 ka0 = *(const short8*)&Kb[rowA + ((quad ^ x7) * 8)];
        const short8 ka1 = *(const short8*)&Kb[rowA + (((4 + quad) ^ x7) * 8)];
        const short8 ka2 = *(const short8*)&Kb[rowB + ((quad ^ x7) * 8)];
        const short8 ka3 = *(const short8*)&Kb[rowB + (((4 + quad) ^ x7) * 8)];
        uint2 vvA[4], vvB[4];
        #pragma unroll
        for (int nt = 0; nt < 4; ++nt) {
            vvA[nt] = *(const uint2*)&Vb[(nt * 16 + l15) * 64 + gA * 8 + (quad & 1) * 4];
            vvB[nt] = *(const uint2*)&Vb[(nt * 16 + l15) * 64 + gB * 8 + (quad & 1) * 4];
        }

        // stage tile j+2 into slot (j+2)&3 = (j-2)&3: idle since tile j-2,
        // reads completed two barriers ago -> safe per the 2-barrier rule.
        if (j < NTILE - 2)
            flash_stage(Kg, Vg, qk_off, vt_off, sh, j + 2,
                        row0, gcol0, row1, gcol1, chunk0, chunk1, lane);

        __builtin_amdgcn_s_setprio(1);
        // QK both groups + exp2 + cvt_pk pack; Q frags from LDS
        uint2 paLo[4], paHi[4];
        #pragma unroll
        for (int g = 0; g < 4; ++g) {
            const int qr = (qh + g * 16 + l15) * 64;
            const short8 qg0 = *(const short8*)&Qs[qr + ((quad ^ x7) * 8)];
            const short8 qg1 = *(const short8*)&Qs[qr + (((4 + quad) ^ x7) * 8)];
            f32x4 t = __builtin_amdgcn_mfma_f32_16x16x32_bf16(ka0, qg0, zero, 0, 0, 0);
            t = __builtin_amdgcn_mfma_f32_16x16x32_bf16(ka1, qg1, t, 0, 0, 0);
            f32x4 u = __builtin_amdgcn_mfma_f32_16x16x32_bf16(ka2, qg0, zero, 0, 0, 0);
            u = __builtin_amdgcn_mfma_f32_16x16x32_bf16(ka3, qg1, u, 0, 0, 0);
            {
                const float p0 = EXP2F(t[0]), p1 = EXP2F(t[1]);
                const float p2 = EXP2F(t[2]), p3 = EXP2F(t[3]);
                lsum[g] += (p0 + p1) + (p2 + p3);
                paLo[g].x = cvtpk(p0, p1);
                paLo[g].y = cvtpk(p2, p3);
            }
            {
                const float p0 = EXP2F(u[0]), p1 = EXP2F(u[1]);
                const float p2 = EXP2F(u[2]), p3 = EXP2F(u[3]);
                lsum[g] += (p0 + p1) + (p2 + p3);
                paHi[g].x = cvtpk(p0, p1);
                paHi[g].y = cvtpk(p2, p3);
            }
        }

        // PV at full K=32: A-frag = {groupA p (slots 0..3), groupB p (4..7)}
        short8 pa8[4];
        #pragma unroll
        for (int g = 0; g < 4; ++g) {
            u32x4 pk;
            pk[0] = paLo[g].x; pk[1] = paLo[g].y;
            pk[2] = paHi[g].x; pk[3] = paHi[g].y;
            pa8[g] = __builtin_bit_cast(short8, pk);
        }
        #pragma unroll
        for (int nt = 0; nt < 4; ++nt) {
            u32x4 vk;
            vk[0] = vvA[nt].x; vk[1] = vvA[nt].y;
            vk[2] = vvB[nt].x; vk[3] = vvB[nt].y;
            const short8 vb8 = __builtin_bit_cast(short8, vk);
            #pragma unroll
            for (int g = 0; g < 4; ++g)
                o[g][nt] = __builtin_amdgcn_mfma_f32_16x16x32_bf16(pa8[g], vb8, o[g][nt], 0, 0, 0);
        }
        __builtin_amdgcn_s_setprio(0);
    }

    // ---- reduction: intra-wave over quads, then 2-way with partner w^1 ----
    #pragma unroll
    for (int g = 0; g < 4; ++g) {
        lsum[g] += __shfl_xor(lsum[g], 16);
        lsum[g] += __shfl_xor(lsum[g], 32);   // now quad-uniform
    }
    __syncthreads();
    float* fb = (float*)sh;                   // 20480 floats available
    if (w & 1) {                              // waves 1,3 export
        #pragma unroll
        for (int g = 0; g < 4; ++g) {
            #pragma unroll
            for (int nt = 0; nt < 4; ++nt)
                #pragma unroll
                for (int r = 0; r < 4; ++r)
                    fb[(w >> 1) * 4096 + g * 1024 + (nt * 4 + r) * 64 + lane] = o[g][nt][r];
            if (quad == 0) fb[8192 + (w >> 1) * 64 + g * 16 + l15] = lsum[g];
        }
    }
    __syncthreads();
    if (!(w & 1)) {                           // waves 0,2 merge + store
        #pragma unroll
        for (int g = 0; g < 4; ++g) {
            #pragma unroll
            for (int nt = 0; nt < 4; ++nt)
                #pragma unroll
                for (int r = 0; r < 4; ++r)
                    o[g][nt][r] += fb[(w >> 1) * 4096 + g * 1024 + (nt * 4 + r) * 64 + lane];
            lsum[g] += fb[8192 + (w >> 1) * 64 + g * 16 + l15];
        }
        #pragma unroll
        for (int g = 0; g < 4; ++g) {
            const float inv = 1.0f / lsum[g];     // q = qh + g*16 + l15
            float invr[4];
            #pragma unroll
            for (int r = 0; r < 4; ++r)
                invr[r] = __shfl(inv, (lane & 0x30) | (quad * 4 + r));
            #pragma unroll
            for (int nt = 0; nt < 4; ++nt) {
                const int e = h * 64 + nt * 16 + l15;
                #pragma unroll
                for (int r = 0; r < 4; ++r) {
                    const int s = q0 + qh + g * 16 + quad * 4 + r;
                    AO[(size_t)(b * S_ + s) * E_ + e] = f2bf(o[g][nt][r] * invr[r]);
                }
            }
        }
    }
}

// ---------------------------------------------------------------------------
extern "C" void kernel_launch(void* const* d_in, const int* in_sizes, int n_in,
                              void* d_out, int out_size, void* d_ws, size_t ws_size,
                              hipStream_t stream) {
    const float* query = (const float*)d_in[0];
    const float* key   = (const float*)d_in[1];
    const float* value = (const float*)d_in[2];
    const float* Wq = (const float*)d_in[3];
    const float* bq = (const float*)d_in[4];
    const float* Wk = (const float*)d_in[5];
    const float* bk = (const float*)d_in[6];
    const float* Wv = (const float*)d_in[7];
    const float* bv = (const float*)d_in[8];
    const float* Wo = (const float*)d_in[9];
    const float* bo = (const float*)d_in[10];
    float* out = (float*)d_out;

    ushort* ws = (ushort*)d_ws;
    ushort* Xq  = ws;
    ushort* Xk  = ws + 4194304u;
    ushort* Xv  = ws + 8388608u;
    ushort* Wqb = ws + 12582912u;
    ushort* Wkb = ws + 13631488u;
    ushort* Wvb = ws + 14680064u;
    ushort* Wob = ws + 15728640u;
    ushort* Qh  = ws + 16777216u;          // [B,H,S,D] (pre-scaled by QSCALE)
    ushort* Kh  = ws + 20971520u;          // [B,H,S,D]
    ushort* Vt  = ws + 25165824u;          // [B,H,D,S]
    ushort* AO  = ws + 29360128u;          // [B,S,E]

    cvt_all<<<8192, 256, 0, stream>>>(query, key, value, Wq, Wk, Wv, Wo, ws);
    gemm_qkv<<<dim3(4, 16, 3), 512, 0, stream>>>(Xq, Xk, Xv, Wqb, Wkb, Wvb,
                                                 bq, bk, bv, Qh, Kh, Vt);
    flash_mfma<<<dim3(S_ / QBLK, H_, B_), 256, 0, stream>>>(Qh, Kh, Vt, AO);
    gemm_out<<<dim3(16, 32), 256, 0, stream>>>(AO, Wob, bo, out);
}

// Round 13
// 205.050 us; speedup vs baseline: 1.1899x; 1.0146x over previous
//
#include <hip/hip_runtime.h>

#define B_ 2
#define S_ 2048
#define E_ 1024
#define H_ 16
#define D_ 64
#define M_ (B_*S_)
#define K_ E_

typedef __attribute__((ext_vector_type(8))) short  short8;
typedef __attribute__((ext_vector_type(4))) float  f32x4;
typedef __attribute__((ext_vector_type(8))) unsigned short u16x8;
typedef __attribute__((ext_vector_type(4))) unsigned short u16x4;
typedef __attribute__((ext_vector_type(4))) unsigned int   u32x4;

// 0.125 * log2(e): folded into Q so scores arrive in exp2 domain
#define QSCALE 0.18033688011112042f

#if __has_builtin(__builtin_amdgcn_exp2f)
#define EXP2F(x) __builtin_amdgcn_exp2f(x)   // raw v_exp_f32
#else
#define EXP2F(x) exp2f(x)
#endif

__device__ __forceinline__ unsigned short f2bf(float f) {   // RNE
    unsigned u = __float_as_uint(f);
    u += 0x7fffu + ((u >> 16) & 1u);
    return (unsigned short)(u >> 16);
}

// 2x f32 -> packed bf16 in one instruction (lo=a, hi=b), RNE.
__device__ __forceinline__ unsigned cvtpk(float a, float b) {
    unsigned r;
    asm("v_cvt_pk_bf16_f32 %0, %1, %2" : "=v"(r) : "v"(a), "v"(b));
    return r;
}

__device__ __forceinline__ void gl_lds16(const ushort* g, ushort* l) {
    __builtin_amdgcn_global_load_lds((const __attribute__((address_space(1))) void*)g,
                                     (__attribute__((address_space(3))) void*)l,
                                     16, 0, 0);
}

// counted-vmcnt barrier: wait for all but the newest N vmem ops, then raw
// s_barrier. RULE (R9/R10/R12 pass, R11 race): an LDS overwrite is only safe
// if the ds_reads of that region were issued >= 2 barriers earlier (or after
// an explicit lgkmcnt(0) drain). All rings below respect 2-barrier separation.
#define FL_SYNC(N) do {                                                   \
    asm volatile("s_waitcnt vmcnt(" #N ")" ::: "memory");                 \
    __builtin_amdgcn_s_barrier();                                         \
    asm volatile("" ::: "memory");                                        \
} while (0)

#define WAITL0_BAR() do {                                                 \
    asm volatile("s_waitcnt lgkmcnt(0)" ::: "memory");                    \
    __builtin_amdgcn_s_barrier();                                         \
    asm volatile("" ::: "memory");                                        \
} while (0)

// ---------------------------------------------------------------------------
// fp32 -> bf16 conversion (all inputs).
// ---------------------------------------------------------------------------
__global__ __launch_bounds__(256)
void cvt_all(const float* __restrict__ q, const float* __restrict__ k,
             const float* __restrict__ v, const float* __restrict__ wq,
             const float* __restrict__ wk, const float* __restrict__ wv,
             const float* __restrict__ wo, ushort* __restrict__ dst)
{
    const int bid = blockIdx.x;
    const float* src;
    size_t dof;
    int local;
    if (bid < 6144) {
        const int t = bid >> 11;
        src = (t == 0) ? q : (t == 1) ? k : v;
        dof = (size_t)t * 4194304u;
        local = bid & 2047;
    } else {
        const int r = bid - 6144;
        const int t = r >> 9;
        src = (t == 0) ? wq : (t == 1) ? wk : (t == 2) ? wv : wo;
        dof = 12582912u + (size_t)t * 1048576u;
        local = r & 511;
    }
    const size_t idx = (size_t)local * 2048 + threadIdx.x * 8;
    const float4 a = *(const float4*)(src + idx);
    const float4 b = *(const float4*)(src + idx + 4);
    u16x8 o;
    o[0] = f2bf(a.x); o[1] = f2bf(a.y); o[2] = f2bf(a.z); o[3] = f2bf(a.w);
    o[4] = f2bf(b.x); o[5] = f2bf(b.y); o[6] = f2bf(b.z); o[7] = f2bf(b.w);
    *(u16x8*)(dst + dof + idx) = o;
}

// ---------------------------------------------------------------------------
// R12 QKV core (kept): 256x256 tile, BK=32, 4-slot counted-vmcnt ring.
// stage(t+2) -> slot (t-2)&3, read two barriers ago (2-barrier rule).
// Steady FL_SYNC(4); zero lgkmcnt(0) drains.
// ---------------------------------------------------------------------------
#define QKV_STAGE(t) do {                                                  \
    ushort* sb_ = sh + ((t) & 3) * 16384;                                  \
    const int k0_ = (t) * 32;                                              \
    gl_lds16(pa0 + k0_, sb_ + ld0);                                        \
    gl_lds16(pa1 + k0_, sb_ + 4096 + ld0);                                 \
    gl_lds16(pb0 + k0_, sb_ + 8192 + ld0);                                 \
    gl_lds16(pb1 + k0_, sb_ + 12288 + ld0);                                \
} while (0)

template<int SWAP>
__device__ __forceinline__ void qkv_core(const ushort* __restrict__ X,
                                         const ushort* __restrict__ W,
                                         int m0, int n0,
                                         f32x4 acc[8][4], ushort* sh)
{
    const int tid  = threadIdx.x;
    const int lane = tid & 63;
    const int w    = tid >> 6;          // 0..7
    const int wm   = w & 1;             // 2 M-waves
    const int wn   = w >> 1;            // 4 N-waves
    const int l15  = lane & 15, quad = lane >> 4;

    const int srow = tid >> 2, cidx = tid & 3;
    const int scol = (cidx ^ (srow & 3)) * 8;
    const ushort* pa0 = X + (size_t)(m0 + srow) * K_ + scol;
    const ushort* pa1 = X + (size_t)(m0 + 128 + srow) * K_ + scol;
    const ushort* pb0 = W + (size_t)(n0 + srow) * K_ + scol;
    const ushort* pb1 = W + (size_t)(n0 + 128 + srow) * K_ + scol;
    const int ld0 = tid * 8;

    const f32x4 zero = {0.f, 0.f, 0.f, 0.f};
    #pragma unroll
    for (int mt = 0; mt < 8; ++mt)
        #pragma unroll
        for (int nt = 0; nt < 4; ++nt) acc[mt][nt] = zero;

    // prologue: stage K-steps 0, 1 (4 ops/thread each)
    QKV_STAGE(0);
    QKV_STAGE(1);

    const int xq = (quad ^ (l15 & 3)) * 8;
    const int arow = wm * 128 + l15;               // + mt*16
    const int brow = wn * 64 + l15;                // + nt*16

    for (int t = 0; t < 32; ++t) {
        ushort* sb = sh + (t & 3) * 16384;

        if (t < 31) { FL_SYNC(4); } else { FL_SYNC(0); }

        short8 bf[4];
        #pragma unroll
        for (int nt = 0; nt < 4; ++nt)
            bf[nt] = *(const short8*)(sb + 8192 + (brow + nt * 16) * 32 + xq);
        short8 af[8];
        #pragma unroll
        for (int mt = 0; mt < 8; ++mt)
            af[mt] = *(const short8*)(sb + (arow + mt * 16) * 32 + xq);

        // stage K-step t+2 into slot (t-2)&3 (read two barriers ago -- safe)
        if (t + 2 < 32) QKV_STAGE(t + 2);

        __builtin_amdgcn_s_setprio(1);
        #pragma unroll
        for (int mt = 0; mt < 8; ++mt)
            #pragma unroll
            for (int nt = 0; nt < 4; ++nt) {
                if (SWAP)
                    acc[mt][nt] = __builtin_amdgcn_mfma_f32_16x16x32_bf16(bf[nt], af[mt], acc[mt][nt], 0, 0, 0);
                else
                    acc[mt][nt] = __builtin_amdgcn_mfma_f32_16x16x32_bf16(af[mt], bf[nt], acc[mt][nt], 0, 0, 0);
            }
        __builtin_amdgcn_s_setprio(0);
    }
}

// QKV projections. z=0: Q -> [B,H,S,D] scaled by QSCALE (swapped, d-contig
// u16x4 stores). z=1: K -> [B,H,S,D] (swapped). z=2: V -> [B,H,D,S].
// R13: T1 XCD swizzle -- grid 192 = 8 x 24 exactly (bijective). Blocks with
// orig ids {k, k+8, ...} live on XCD k; remap tile=(id&7)*24+(id>>3) so each
// XCD gets 24 CONSECUTIVE tiles: the 4 tiles sharing a 512 KB X-panel land
// on one XCD's L2 instead of 4 different ones.
__global__ __launch_bounds__(512, 2)
void gemm_qkv(const ushort* __restrict__ Xq, const ushort* __restrict__ Xk,
              const ushort* __restrict__ Xv, const ushort* __restrict__ Wq,
              const ushort* __restrict__ Wk, const ushort* __restrict__ Wv,
              const float* __restrict__ bq, const float* __restrict__ bk,
              const float* __restrict__ bv, ushort* __restrict__ Qh,
              ushort* __restrict__ Kh, ushort* __restrict__ Vt)
{
    __shared__ ushort sh[65536];                   // 128 KB: 4 slots x 32 KB
    const int id = blockIdx.z * 64 + blockIdx.y * 4 + blockIdx.x;
    const int tile = (id & 7) * 24 + (id >> 3);    // bijective: 192 = 8*24
    const int z = tile >> 6;                       // tile / 64
    const int rem = tile & 63;
    const int m0 = (rem >> 2) * 256, n0 = (rem & 3) * 256;

    const ushort* X = (z == 0) ? Xq : (z == 1) ? Xk : Xv;
    const ushort* W = (z == 0) ? Wq : (z == 1) ? Wk : Wv;
    const float* bias = (z == 0) ? bq : (z == 1) ? bk : bv;
    ushort* dst = (z == 0) ? Qh : (z == 1) ? Kh : Vt;

    f32x4 acc[8][4];
    const int lane = threadIdx.x & 63, w = threadIdx.x >> 6;
    const int wm = w & 1, wn = w >> 1;
    const int l15 = lane & 15, quad = lane >> 4;

    if (z < 2) {
        qkv_core<1>(X, W, m0, n0, acc, sh);
        const float qsc = (z == 0) ? QSCALE : 1.0f;
        #pragma unroll
        for (int nt = 0; nt < 4; ++nt) {
            const int nb = n0 + wn * 64 + nt * 16 + quad * 4;   // feature dim
            const int h = nb >> 6, d0 = nb & 63;
            const float4 b4 = *(const float4*)(bias + nb);
            const float bb4[4] = {b4.x, b4.y, b4.z, b4.w};
            #pragma unroll
            for (int mt = 0; mt < 8; ++mt) {
                const int tok = m0 + wm * 128 + mt * 16 + l15;
                const int b = tok >> 11, s = tok & (S_ - 1);
                u16x4 pk;
                #pragma unroll
                for (int r = 0; r < 4; ++r)
                    pk[r] = f2bf((acc[mt][nt][r] + bb4[r]) * qsc);
                *(u16x4*)&dst[(((size_t)(b * H_ + h) * S_) + s) * D_ + d0] = pk;
            }
        }
    } else {
        qkv_core<0>(X, W, m0, n0, acc, sh);
        float bias4[4];
        #pragma unroll
        for (int nt = 0; nt < 4; ++nt)
            bias4[nt] = bias[n0 + wn * 64 + nt * 16 + l15];
        #pragma unroll
        for (int mt = 0; mt < 8; ++mt) {
            const int mrow0 = m0 + wm * 128 + mt * 16 + (quad * 4);
            const int b = mrow0 >> 11;
            const int s0 = mrow0 & (S_ - 1);
            #pragma unroll
            for (int nt = 0; nt < 4; ++nt) {
                const int n = n0 + wn * 64 + nt * 16 + l15;
                const int h = n >> 6, d = n & 63;
                u16x4 pk;
                #pragma unroll
                for (int r = 0; r < 4; ++r) pk[r] = f2bf(acc[mt][nt][r] + bias4[nt]);
                *(u16x4*)&Vt[(((size_t)(b * H_ + h) * D_) + d) * S_ + s0] = pk;
            }
        }
    }
}

// ---------------------------------------------------------------------------
// Final projection R10 ring (kept) + R13 T1 XCD swizzle: grid 512 = 8 x 64
// (bijective). Each XCD gets 64 consecutive tiles = 4 full A-panels; the 16
// blocks sharing an A-panel co-locate on one XCD's L2.
// ---------------------------------------------------------------------------
__global__ __launch_bounds__(256)
void gemm_out(const ushort* __restrict__ X, const ushort* __restrict__ W,
              const float* __restrict__ bias, float* __restrict__ out)
{
    __shared__ ushort sh[24576];       // 48 KB: 4 slots x 6144 ushorts
    const int id = blockIdx.y * 16 + blockIdx.x;
    const int tile = (id & 7) * 64 + (id >> 3);    // bijective: 512 = 8*64
    const int m0 = (tile >> 4) * 128, n0 = (tile & 15) * 64;

    const int tid = threadIdx.x, lane = tid & 63, w = tid >> 6;
    const int wm = w & 1, wn = w >> 1;
    const int l15 = lane & 15, quad = lane >> 4;
    const int r0 = tid >> 2, c8 = (tid & 3) * 8;
    const int kb = quad * 8;

    const ushort* ga = X + (size_t)(m0 + r0) * K_ + c8;
    const ushort* gb = W + (size_t)(n0 + r0) * K_ + c8;

    const f32x4 zero = {0.f, 0.f, 0.f, 0.f};
    f32x4 acc[4][2];
    #pragma unroll
    for (int mt = 0; mt < 4; ++mt)
        #pragma unroll
        for (int nt = 0; nt < 2; ++nt) acc[mt][nt] = zero;

    // prologue: stage K-steps 0 and 1 (3 ops/thread each)
    #pragma unroll
    for (int t0 = 0; t0 < 2; ++t0) {
        ushort* sb = sh + t0 * 6144;
        gl_lds16(ga + t0 * 32,                 sb + tid * 8);
        gl_lds16(ga + t0 * 32 + (size_t)64 * K_, sb + 2048 + tid * 8);
        gl_lds16(gb + t0 * 32,                 sb + 4096 + tid * 8);
    }

    for (int t = 0; t < 32; ++t) {
        ushort* sb = sh + (t & 3) * 6144;

        if (t < 31) { FL_SYNC(3); } else { FL_SYNC(0); }

        short8 af[4], bf[2];
        #pragma unroll
        for (int mt = 0; mt < 4; ++mt)
            af[mt] = *(const short8*)(sb + (wm * 64 + mt * 16 + l15) * 32 + kb);
        #pragma unroll
        for (int nt = 0; nt < 2; ++nt)
            bf[nt] = *(const short8*)(sb + 4096 + (wn * 32 + nt * 16 + l15) * 32 + kb);

        if (t + 2 < 32) {
            ushort* nb = sh + ((t + 2) & 3) * 6144;
            const int k0 = (t + 2) * 32;
            gl_lds16(ga + k0,                 nb + tid * 8);
            gl_lds16(ga + k0 + (size_t)64 * K_, nb + 2048 + tid * 8);
            gl_lds16(gb + k0,                 nb + 4096 + tid * 8);
        }

        __builtin_amdgcn_s_setprio(1);
        #pragma unroll
        for (int mt = 0; mt < 4; ++mt)
            #pragma unroll
            for (int nt = 0; nt < 2; ++nt)
                acc[mt][nt] = __builtin_amdgcn_mfma_f32_16x16x32_bf16(af[mt], bf[nt], acc[mt][nt], 0, 0, 0);
        __builtin_amdgcn_s_setprio(0);
    }

    float bias2[2];
    #pragma unroll
    for (int nt = 0; nt < 2; ++nt)
        bias2[nt] = bias[n0 + wn * 32 + nt * 16 + l15];

    #pragma unroll
    for (int mt = 0; mt < 4; ++mt) {
        const int mrow0 = m0 + wm * 64 + mt * 16 + quad * 4;
        #pragma unroll
        for (int nt = 0; nt < 2; ++nt) {
            const int n = n0 + wn * 32 + nt * 16 + l15;
            #pragma unroll
            for (int r = 0; r < 4; ++r)
                out[(size_t)(mrow0 + r) * E_ + n] = acc[mt][nt][r] + bias2[nt];
        }
    }
}

// ---------------------------------------------------------------------------
// Flash attention: R9/R10 config kept verbatim (46.6us at full clock; R12's
// 56.5 reading was a uniform-rate clock artifact -- all rate counters -17%
// at identical bytes/work). q-split QBLK=128, 4-slot ring, counted vmcnt,
// cvt_pk, setprio. Spill guard: WRITE_SIZE == 8192 KB.
// ---------------------------------------------------------------------------
#define NTILE (S_ / 64)
#define QBLK 128

__device__ __forceinline__ void flash_stage(const ushort* __restrict__ Kg,
                                            const ushort* __restrict__ Vg,
                                            size_t qk_off, size_t vt_off,
                                            ushort* sh, int j,
                                            int row0, int gcol0, int row1, int gcol1,
                                            int chunk0, int chunk1, int lane)
{
    ushort* sb = sh + 8192 + (j & 3) * 8192;
    const int j0n = j * 64;
    gl_lds16(Kg + qk_off + (size_t)(j0n + row0) * D_ + gcol0 * 8, sb + chunk0 * 512 + lane * 8);
    gl_lds16(Vg + vt_off + (size_t)row0 * S_ + j0n + gcol0 * 8, sb + 4096 + chunk0 * 512 + lane * 8);
    gl_lds16(Kg + qk_off + (size_t)(j0n + row1) * D_ + gcol1 * 8, sb + chunk1 * 512 + lane * 8);
    gl_lds16(Vg + vt_off + (size_t)row1 * S_ + j0n + gcol1 * 8, sb + 4096 + chunk1 * 512 + lane * 8);
}

__global__ __launch_bounds__(256, 2)
void flash_mfma(const ushort* __restrict__ Qg, const ushort* __restrict__ Kg,
                const ushort* __restrict__ Vg, ushort* __restrict__ AO)
{
    // 80 KB: Qs(8192 u = 128x64) | slot r at 8192 + r*8192: K(4096 u), V(4096 u)
    __shared__ ushort sh[40960];
    ushort* Qs = sh;

    const int tid = threadIdx.x, lane = tid & 63, w = tid >> 6;
    const int l15 = lane & 15, quad = lane >> 4;
    const int q0 = blockIdx.x * QBLK, h = blockIdx.y, b = blockIdx.z;
    const size_t qk_off = (size_t)(b * H_ + h) * S_ * D_;   // [s][d]
    const size_t vt_off = (size_t)(b * H_ + h) * D_ * S_;   // [d][s]

    const int chunk0 = w, chunk1 = w + 4;
    const int row0 = chunk0 * 8 + (lane >> 3);
    const int row1 = chunk1 * 8 + (lane >> 3);
    const int gcol0 = (lane & 7) ^ (row0 & 7);
    const int gcol1 = (lane & 7) ^ (row1 & 7);

    // prologue: Q (4 ops, 128 rows), then K/V tiles 0,1 (4 ops each)
    #pragma unroll
    for (int i = 0; i < 4; ++i) {
        const int qc = w + i * 4;                  // 16 chunks of 8 rows
        const int qrow = qc * 8 + (lane >> 3);
        const int qg = (lane & 7) ^ (qrow & 7);
        gl_lds16(Qg + qk_off + (size_t)(q0 + qrow) * D_ + qg * 8,
                 Qs + qc * 512 + lane * 8);
    }
    flash_stage(Kg, Vg, qk_off, vt_off, sh, 0, row0, gcol0, row1, gcol1, chunk0, chunk1, lane);
    flash_stage(Kg, Vg, qk_off, vt_off, sh, 1, row0, gcol0, row1, gcol1, chunk0, chunk1, lane);

    FL_SYNC(8);                        // Q landed (tiles 0,1 = 8 ops in flight)

    f32x4 o[4][4];                     // o[g][nt]: O[q=qh+g*16+quad*4+r][d=nt*16+l15]
    #pragma unroll
    for (int g = 0; g < 4; ++g)
        #pragma unroll
        for (int nt = 0; nt < 4; ++nt) o[g][nt] = {0.f, 0.f, 0.f, 0.f};
    float lsum[4] = {0.f, 0.f, 0.f, 0.f};  // partial denom, q = qh + g*16 + l15

    const int qh  = (w >> 1) * 64;         // q-half base
    const int kvb = (w & 1) * 32;          // kv-half base within tile
    const int x7  = l15 & 7;
    const int rowA = (kvb + l15) * 64;          // K rows, group A (kv 16-group 0)
    const int rowB = (kvb + 16 + l15) * 64;     // group B
    const int gA = ((w & 1) * 4 + (quad >> 1)) ^ x7;        // V col-group, A
    const int gB = ((w & 1) * 4 + 2 + (quad >> 1)) ^ x7;    // B
    const f32x4 zero = {0.f, 0.f, 0.f, 0.f};

    for (int j = 0; j < NTILE; ++j) {
        const ushort* Kb = sh + 8192 + (j & 3) * 8192;
        const ushort* Vb = Kb + 4096;
        if (j < NTILE - 1) { FL_SYNC(4); } else { FL_SYNC(0); }

        // K frags (both kv-16-groups of this wave's half) + V frags
        const short8 ka0 = *(const short8*)&Kb[rowA + ((quad ^ x7) * 8)];
        const short8 ka1 = *(const short8*)&Kb[rowA + (((4 + quad) ^ x7) * 8)];
        const short8 ka2 = *(const short8*)&Kb[rowB + ((quad ^ x7) * 8)];
        const short8 ka3 = *(const short8*)&Kb[rowB + (((4 + quad) ^ x7) * 8)];
        uint2 vvA[4], vvB[4];
        #pragma unroll
        for (int nt = 0; nt < 4; ++nt) {
            vvA[nt] = *(const uint2*)&Vb[(nt * 16 + l15) * 64 + gA * 8 + (quad & 1) * 4];
            vvB[nt] = *(const uint2*)&Vb[(nt * 16 + l15) * 64 + gB * 8 + (quad & 1) * 4];
        }

        // stage tile j+2 into slot (j+2)&3 = (j-2)&3: idle since tile j-2,
        // reads completed two barriers ago -> safe per the 2-barrier rule.
        if (j < NTILE - 2)
            flash_stage(Kg, Vg, qk_off, vt_off, sh, j + 2,
                        row0, gcol0, row1, gcol1, chunk0, chunk1, lane);

        __builtin_amdgcn_s_setprio(1);
        // QK both groups + exp2 + cvt_pk pack; Q frags from LDS
        uint2 paLo[4], paHi[4];
        #pragma unroll
        for (int g = 0; g < 4; ++g) {
            const int qr = (qh + g * 16 + l15) * 64;
            const short8 qg0 = *(const short8*)&Qs[qr + ((quad ^ x7) * 8)];
            const short8 qg1 = *(const short8*)&Qs[qr + (((4 + quad) ^ x7) * 8)];
            f32x4 t = __builtin_amdgcn_mfma_f32_16x16x32_bf16(ka0, qg0, zero, 0, 0, 0);
            t = __builtin_amdgcn_mfma_f32_16x16x32_bf16(ka1, qg1, t, 0, 0, 0);
            f32x4 u = __builtin_amdgcn_mfma_f32_16x16x32_bf16(ka2, qg0, zero, 0, 0, 0);
            u = __builtin_amdgcn_mfma_f32_16x16x32_bf16(ka3, qg1, u, 0, 0, 0);
            {
                const float p0 = EXP2F(t[0]), p1 = EXP2F(t[1]);
                const float p2 = EXP2F(t[2]), p3 = EXP2F(t[3]);
                lsum[g] += (p0 + p1) + (p2 + p3);
                paLo[g].x = cvtpk(p0, p1);
                paLo[g].y = cvtpk(p2, p3);
            }
            {
                const float p0 = EXP2F(u[0]), p1 = EXP2F(u[1]);
                const float p2 = EXP2F(u[2]), p3 = EXP2F(u[3]);
                lsum[g] += (p0 + p1) + (p2 + p3);
                paHi[g].x = cvtpk(p0, p1);
                paHi[g].y = cvtpk(p2, p3);
            }
        }

        // PV at full K=32: A-frag = {groupA p (slots 0..3), groupB p (4..7)}
        short8 pa8[4];
        #pragma unroll
        for (int g = 0; g < 4; ++g) {
            u32x4 pk;
            pk[0] = paLo[g].x; pk[1] = paLo[g].y;
            pk[2] = paHi[g].x; pk[3] = paHi[g].y;
            pa8[g] = __builtin_bit_cast(short8, pk);
        }
        #pragma unroll
        for (int nt = 0; nt < 4; ++nt) {
            u32x4 vk;
            vk[0] = vvA[nt].x; vk[1] = vvA[nt].y;
            vk[2] = vvB[nt].x; vk[3] = vvB[nt].y;
            const short8 vb8 = __builtin_bit_cast(short8, vk);
            #pragma unroll
            for (int g = 0; g < 4; ++g)
                o[g][nt] = __builtin_amdgcn_mfma_f32_16x16x32_bf16(pa8[g], vb8, o[g][nt], 0, 0, 0);
        }
        __builtin_amdgcn_s_setprio(0);
    }

    // ---- reduction: intra-wave over quads, then 2-way with partner w^1 ----
    #pragma unroll
    for (int g = 0; g < 4; ++g) {
        lsum[g] += __shfl_xor(lsum[g], 16);
        lsum[g] += __shfl_xor(lsum[g], 32);   // now quad-uniform
    }
    __syncthreads();
    float* fb = (float*)sh;                   // 20480 floats available
    if (w & 1) {                              // waves 1,3 export
        #pragma unroll
        for (int g = 0; g < 4; ++g) {
            #pragma unroll
            for (int nt = 0; nt < 4; ++nt)
                #pragma unroll
                for (int r = 0; r < 4; ++r)
                    fb[(w >> 1) * 4096 + g * 1024 + (nt * 4 + r) * 64 + lane] = o[g][nt][r];
            if (quad == 0) fb[8192 + (w >> 1) * 64 + g * 16 + l15] = lsum[g];
        }
    }
    __syncthreads();
    if (!(w & 1)) {                           // waves 0,2 merge + store
        #pragma unroll
        for (int g = 0; g < 4; ++g) {
            #pragma unroll
            for (int nt = 0; nt < 4; ++nt)
                #pragma unroll
                for (int r = 0; r < 4; ++r)
                    o[g][nt][r] += fb[(w >> 1) * 4096 + g * 1024 + (nt * 4 + r) * 64 + lane];
            lsum[g] += fb[8192 + (w >> 1) * 64 + g * 16 + l15];
        }
        #pragma unroll
        for (int g = 0; g < 4; ++g) {
            const float inv = 1.0f / lsum[g];     // q = qh + g*16 + l15
            float invr[4];
            #pragma unroll
            for (int r = 0; r < 4; ++r)
                invr[r] = __shfl(inv, (lane & 0x30) | (quad * 4 + r));
            #pragma unroll
            for (int nt = 0; nt < 4; ++nt) {
                const int e = h * 64 + nt * 16 + l15;
                #pragma unroll
                for (int r = 0; r < 4; ++r) {
                    const int s = q0 + qh + g * 16 + quad * 4 + r;
                    AO[(size_t)(b * S_ + s) * E_ + e] = f2bf(o[g][nt][r] * invr[r]);
                }
            }
        }
    }
}

// ---------------------------------------------------------------------------
extern "C" void kernel_launch(void* const* d_in, const int* in_sizes, int n_in,
                              void* d_out, int out_size, void* d_ws, size_t ws_size,
                              hipStream_t stream) {
    const float* query = (const float*)d_in[0];
    const float* key   = (const float*)d_in[1];
    const float* value = (const float*)d_in[2];
    const float* Wq = (const float*)d_in[3];
    const float* bq = (const float*)d_in[4];
    const float* Wk = (const float*)d_in[5];
    const float* bk = (const float*)d_in[6];
    const float* Wv = (const float*)d_in[7];
    const float* bv = (const float*)d_in[8];
    const float* Wo = (const float*)d_in[9];
    const float* bo = (const float*)d_in[10];
    float* out = (float*)d_out;

    ushort* ws = (ushort*)d_ws;
    ushort* Xq  = ws;
    ushort* Xk  = ws + 4194304u;
    ushort* Xv  = ws + 8388608u;
    ushort* Wqb = ws + 12582912u;
    ushort* Wkb = ws + 13631488u;
    ushort* Wvb = ws + 14680064u;
    ushort* Wob = ws + 15728640u;
    ushort* Qh  = ws + 16777216u;          // [B,H,S,D] (pre-scaled by QSCALE)
    ushort* Kh  = ws + 20971520u;          // [B,H,S,D]
    ushort* Vt  = ws + 25165824u;          // [B,H,D,S]
    ushort* AO  = ws + 29360128u;          // [B,S,E]

    cvt_all<<<8192, 256, 0, stream>>>(query, key, value, Wq, Wk, Wv, Wo, ws);
    gemm_qkv<<<dim3(4, 16, 3), 512, 0, stream>>>(Xq, Xk, Xv, Wqb, Wkb, Wvb,
                                                 bq, bk, bv, Qh, Kh, Vt);
    flash_mfma<<<dim3(S_ / QBLK, H_, B_), 256, 0, stream>>>(Qh, Kh, Vt, AO);
    gemm_out<<<dim3(16, 32), 256, 0, stream>>>(AO, Wob, bo, out);
}